// Round 12
// baseline (5435.288 us; speedup 1.0000x reference)
//
#include <hip/hip_runtime.h>
#include <hip/hip_bf16.h>
#include <type_traits>
#include <stdint.h>

#define AS1 __attribute__((address_space(1)))
#define AS3 __attribute__((address_space(3)))

typedef __attribute__((ext_vector_type(8))) short short8;
typedef __attribute__((ext_vector_type(4))) short short4v;
typedef __attribute__((ext_vector_type(4))) float floatx4;

#define B_DIM 8
#define S_DIM 4096
#define H_DIM 1024
#define M_DIM 1024

__device__ __forceinline__ float b2f(short s) {
  union { unsigned u; float f; } x;
  x.u = ((unsigned)(unsigned short)s) << 16;
  return x.f;
}
__device__ __forceinline__ short f2b(float f) {
  union { float f; unsigned u; } x;
  x.f = f;
  unsigned u = x.u;
  unsigned r = (u + 0x7fffu + ((u >> 16) & 1u)) >> 16;  // RNE
  return (short)(unsigned short)r;
}

// Clobber-free sync primitives (measured safe r7-r11).
#define SCHEDB() __builtin_amdgcn_sched_barrier(0)
#define VMCNT(N) asm volatile("s_waitcnt vmcnt(" #N ")")
#define BARRIER() do { SCHEDB(); __builtin_amdgcn_s_barrier(); SCHEDB(); } while (0)

__device__ __forceinline__ void async16(const void* g, void* l) {
  __builtin_amdgcn_global_load_lds((const AS1 void*)g, (AS3 void*)l, 16, 0, 0);
}

// ---------------- f32 -> bf16 convert (hidden states) ----------------
__global__ __launch_bounds__(256) void k_cvt(const float4* __restrict__ in,
                                             short4v* __restrict__ out, int n4) {
  const int stride = gridDim.x * 256;
  for (int i = blockIdx.x * 256 + threadIdx.x; i < n4; i += stride) {
    float4 v = in[i];
    short4v o = { f2b(v.x), f2b(v.y), f2b(v.z), f2b(v.w) };
    out[i] = o;
  }
}

// ---------------- all four weight converts in one launch ----------------
__global__ __launch_bounds__(256) void k_cvtw(const float4* __restrict__ Wq,
                                              const float4* __restrict__ Wk,
                                              const float4* __restrict__ Wv,
                                              const float4* __restrict__ Wo,
                                              short4v* __restrict__ wq,
                                              short4v* __restrict__ wk,
                                              short4v* __restrict__ wv,
                                              short4v* __restrict__ wo) {
  const int stride = gridDim.x * 256;
  for (int i = blockIdx.x * 256 + threadIdx.x; i < 1310720; i += stride) {
    const float4* src; short4v* dst; int j;
    if (i < 262144)      { src = Wq; dst = wq; j = i; }
    else if (i < 524288) { src = Wk; dst = wk; j = i - 262144; }
    else if (i < 786432) { src = Wv; dst = wv; j = i - 524288; }
    else                 { src = Wo; dst = wo; j = i - 786432; }
    float4 v = src[j];
    short4v o = { f2b(v.x), f2b(v.y), f2b(v.z), f2b(v.w) };
    dst[j] = o;
  }
}

// ============ 256x256 GEMM: A via LDS (64 KiB, 2 blocks/CU), B via global->reg ============
// C[r][n] = sum_k A[r][k] * B[n][k] (+bias[n]).
// AMODE 0: A direct (row stride lda). 1: gathered rows (r -> b*4096 + (m*4095)/1023), K=1024.
//       2: A concat(A, A2), each row stride 1024, K=2048.
//       3: AMODE-2 A-side + B-side switch: k<1024 -> Bw (stride ldb); k>=1024 -> B2 + (row0>>12)*1M (stride 1024).
// EPI 0: C[row*1024 + n] (OutT). 1: KV natural split: col<1024 -> C; else Cv.
// A-stage rotation: A1,A3(t+1)@PH0 (2 calls, buf^1); A0,A2(t+2)@PH3 (2 calls, buf).
// B-reg loads: bfQ=bf(k1,t)@PH0; bfP=bf(k0,t+1)@PH2 (4 dwordx4 each, L2-resident panels).
// vmcnt ledger (queue [P3SA2][P0BL4][P0SA2][P2BL4]): VMCNT(8)@PH0, VMCNT(6)@PH2, VMCNT(6)@PH3.
template<int AMODE, int EPI, bool HAS_BIAS, typename OutT>
__global__ __launch_bounds__(512, 4)
void k_gemm256(const short* __restrict__ A, const short* __restrict__ A2,
               const short* __restrict__ Bw, const short* __restrict__ B2,
               const float* __restrict__ bias, const float* __restrict__ bias2,
               OutT* __restrict__ C, short* __restrict__ Cv,
               int K, long lda, long ldb, long sA, long sB, long sC)
{
  // A only: [buf][256 rows][64 shorts]; row = 128B, XOR-swizzled by ((row&7)<<4). 64 KiB.
  __shared__ __align__(16) short lds[2][256 * 64];

  const int t512 = threadIdx.x;
  const int l = t512 & 63;
  const int w = t512 >> 6;            // wave 0..7
  const int wm = w >> 2, wn = w & 3;  // 2M x 4N wave grid
  const int z = blockIdx.z;

  // XCD-aware bijective chunk swizzle, col-fastest within chunk (A-panel reuse).
  const int gx = gridDim.x, gy = gridDim.y;
  const int orig = blockIdx.y * gx + blockIdx.x;
  const int nwg = gx * gy;
  int s = orig;
  if ((nwg & 7) == 0) {
    const int q8 = nwg >> 3;
    s = (orig & 7) * q8 + (orig >> 3);
  }
  const int row0 = (s / gy) * 256;
  const int col0 = (s % gy) * 256;

  const short* Az = A + (size_t)z * sA;
  const short* Bz = Bw + (size_t)z * sB;

  // staging geometry: one call = 64 rows x 128B = 8KB = 512 threads x 16B
  const int rloc = t512 >> 3;              // row within call, 0..63
  const int slot = t512 & 7;               // 16B slot
  const int sw = slot ^ (rloc & 7);        // pre-swizzled source slot
  const int nt = K >> 6;                   // K-tiles of 64

  // ds_read geometry (A)
  const int lr = l & 15;
  const int lkb = (l >> 4) << 4;           // 0,16,32,48 (bytes)
  const int aswz = (lr & 7) << 4;
  const int aRowByte = (wm * 128 + lr) * 128;

  // B per-lane reg-load bases (row = col0 + wn*64 + ni*16 + lr; 8 shorts at k-slot (l>>4)*8)
  const short* bb1;
  const short* bb2 = nullptr;
  if constexpr (AMODE == 3) {
    bb1 = Bw + (size_t)(col0 + wn * 64 + lr) * ldb + (l >> 4) * 8;
    bb2 = B2 + (size_t)(row0 >> 12) * 1048576 + (size_t)(col0 + wn * 64 + lr) * 1024 + (l >> 4) * 8;
  } else {
    bb1 = Bz + (size_t)(col0 + wn * 64 + lr) * ldb + (l >> 4) * 8;
  }

  auto srcA = [&](int R, int tile) -> const char* {
    if constexpr (AMODE == 2 || AMODE == 3) {
      const size_t row = (size_t)(row0 + R + rloc);
      if (tile < 16) return (const char*)A  + ((row * 1024 + (size_t)tile * 64) << 1) + (sw << 4);
      else           return (const char*)A2 + ((row * 1024 + (size_t)(tile - 16) * 64) << 1) + (sw << 4);
    } else if constexpr (AMODE == 1) {
      const int r = row0 + R + rloc;
      const unsigned m = (unsigned)(r & (M_DIM - 1));
      const int g = (r >> 10) * S_DIM + (int)((m * 4095u) / 1023u);
      return (const char*)A + (((size_t)g * H_DIM + (size_t)tile * 64) << 1) + (sw << 4);
    } else {
      return (const char*)Az + (((size_t)(row0 + R + rloc) * lda + (size_t)tile * 64) << 1) + (sw << 4);
    }
  };
  auto SA = [&](int buf, int R, int tile) {
    async16(srcA(R, tile), (char*)&lds[buf][0] + (size_t)(R + w * 8) * 128);
  };

  floatx4 acc[8][4];
  #pragma unroll
  for (int i = 0; i < 8; ++i)
    #pragma unroll
    for (int j = 0; j < 4; ++j)
      acc[i][j] = (floatx4){0.f, 0.f, 0.f, 0.f};

#define BL4(dst, tile, ks)                                                        \
  {                                                                               \
    if constexpr (AMODE == 3) {                                                   \
      if ((tile) < 16) {                                                          \
        _Pragma("unroll")                                                         \
        for (int ni = 0; ni < 4; ++ni)                                            \
          dst[ni] = *(const short8*)(bb1 + (size_t)ni * 16 * ldb +                \
                                     (size_t)(tile) * 64 + (ks) * 32);            \
      } else {                                                                    \
        _Pragma("unroll")                                                         \
        for (int ni = 0; ni < 4; ++ni)                                            \
          dst[ni] = *(const short8*)(bb2 + (size_t)ni * 16 * 1024 +               \
                                     (size_t)((tile) - 16) * 64 + (ks) * 32);     \
      }                                                                           \
    } else {                                                                      \
      _Pragma("unroll")                                                           \
      for (int ni = 0; ni < 4; ++ni)                                              \
        dst[ni] = *(const short8*)(bb1 + (size_t)ni * 16 * ldb +                  \
                                   (size_t)(tile) * 64 + (ks) * 32);              \
    }                                                                             \
  }
#define RD_A4(dst, ldsbase, Mh, ks)                                               \
  {                                                                               \
    _Pragma("unroll")                                                             \
    for (int mi = 0; mi < 4; ++mi)                                                \
      dst[mi] = *(const short8*)((ldsbase) + aRowByte + (Mh) * 8192 +             \
                                 mi * 2048 + ((((ks) * 64) + lkb) ^ aswz));       \
  }
#define MFMA16(Mh, av, bv)                                                        \
  {                                                                               \
    __builtin_amdgcn_s_setprio(1);                                                \
    _Pragma("unroll")                                                             \
    for (int mi = 0; mi < 4; ++mi)                                                \
      _Pragma("unroll")                                                           \
      for (int ni = 0; ni < 4; ++ni)                                              \
        acc[(Mh) * 4 + mi][ni] = __builtin_amdgcn_mfma_f32_16x16x32_bf16(         \
            av[mi], bv[ni], acc[(Mh) * 4 + mi][ni], 0, 0, 0);                     \
    __builtin_amdgcn_s_setprio(0);                                                \
  }

  short8 afX[4], afY[4], bfP[4], bfQ[4];

  // ---- prologue: tile0 full A (4) -> buf0; BL bfP(k0,t0); A0,A2 of t1 -> buf1 ----
  {
    const int t1 = (nt > 1) ? 1 : 0;
    SA(0, 0, 0); SA(0, 64, 0); SA(0, 128, 0); SA(0, 192, 0);
    BL4(bfP, 0, 0);
    SA(1, 0, t1); SA(1, 128, t1);
    SCHEDB();
    VMCNT(2);                      // tile0 A + bfP landed; keep A0A2(t1) pair in flight
    BARRIER();
    const char* L0A = (const char*)&lds[0][0];
    RD_A4(afX, L0A, 0, 0);         // q0 of t0
  }

  for (int t = 0; t < nt; ++t) {
    const int b = t & 1;
    const char* LA  = (const char*)&lds[b][0];
    const char* LA1 = (const char*)&lds[b ^ 1][0];
    const int tn  = (t + 1 < nt) ? t + 1 : nt - 1;
    const int tn2 = (t + 2 < nt) ? t + 2 : nt - 1;

    // ---- PH0: read q1 A; BL bfQ=bf(k1,t); stage A1,A3(t+1) -> buf^1 ----
    RD_A4(afY, LA, 1, 0);
    BL4(bfQ, t, 1);
    SA(b ^ 1, 64, tn); SA(b ^ 1, 192, tn);
    SCHEDB();
    VMCNT(8);                      // drains P2(t-1) BL: bfP ready for this MFMA
    BARRIER();
    MFMA16(0, afX, bfP);           // q0 = (Mh0,k0)
    BARRIER();

    // ---- PH1: read q2 A ----
    RD_A4(afX, LA, 0, 1);
    BARRIER();
    MFMA16(1, afY, bfP);           // q1 = (Mh1,k0)
    BARRIER();

    // ---- PH2: read q3 A; BL bfP=bf(k0,t+1) ----
    RD_A4(afY, LA, 1, 1);
    BL4(bfP, tn, 0);
    SCHEDB();
    VMCNT(6);                      // drains P0 BL (bfQ ready) + P3(t-1) SA (A0A2(t+1) in LDS)
    BARRIER();
    MFMA16(0, afX, bfQ);           // q2 = (Mh0,k1)
    BARRIER();

    // ---- PH3: read q0(t+1) from buf^1; stage A0,A2(t+2) -> buf ----
    RD_A4(afX, LA1, 0, 0);
    SA(b, 0, tn2); SA(b, 128, tn2);
    BARRIER();
    MFMA16(1, afY, bfQ);           // q3 = (Mh1,k1)
    SCHEDB();
    VMCNT(6);                      // drains P0 SA: A1,A3(t+1) in LDS for PH0(t+1) reads
    BARRIER();
  }
#undef RD_A4
#undef BL4
#undef MFMA16

  SCHEDB();
  VMCNT(0);  // drain leftover prefetches
  SCHEDB();

  OutT* Cz = C + (size_t)z * sC;
  const int rsub = (l >> 4) * 4;
  #pragma unroll
  for (int ni = 0; ni < 4; ++ni) {
    const int colg = col0 + wn * 64 + ni * 16 + lr;
    float bvv = 0.f;
    if constexpr (HAS_BIAS) {
      if constexpr (EPI == 1) bvv = (colg < 1024) ? bias[colg] : bias2[colg - 1024];
      else bvv = bias[colg];
    }
    #pragma unroll
    for (int m = 0; m < 8; ++m) {
      const int rg = row0 + wm * 128 + (m >> 2) * 64 + (m & 3) * 16 + rsub;
      #pragma unroll
      for (int j = 0; j < 4; ++j) {
        const float v = acc[m][ni][j] + bvv;
        const int rr = rg + j;
        if constexpr (EPI == 1) {
          if (colg < 1024) ((short*)C)[(size_t)rr * 1024 + colg] = f2b(v);
          else             Cv[(size_t)rr * 1024 + (colg - 1024)] = f2b(v);
        } else {
          const size_t o = (size_t)rr * 1024 + colg;
          if constexpr (std::is_same<OutT, float>::value) Cz[o] = v;
          else Cz[o] = f2b(v);
        }
      }
    }
  }
}

// ---------------- row inverse-L2-norm (read-only): inv[row] = 1/max(|x_row|,1e-12) ----------------
__global__ __launch_bounds__(256) void k_rownorm(const short* __restrict__ x,
                                                 float* __restrict__ inv) {
  const int w = threadIdx.x >> 6, l = threadIdx.x & 63;
  const size_t row = (size_t)blockIdx.x * 4 + w;
  const short* p = x + row * 1024 + l * 16;
  short8 v0 = *(const short8*)p;
  short8 v1 = *(const short8*)(p + 8);
  float ss = 0.f;
  #pragma unroll
  for (int i = 0; i < 8; ++i) {
    const float a = b2f(v0[i]), b = b2f(v1[i]);
    ss += a * a + b * b;
  }
  #pragma unroll
  for (int o = 32; o > 0; o >>= 1) ss += __shfl_xor(ss, o, 64);
  if (l == 0) inv[row] = 1.f / fmaxf(sqrtf(ss), 1e-12f);
}

// ---------------- softmax over rows of 1024 (bf16 sb -> bf16 ab) with norm folding ----------------
__global__ __launch_bounds__(256) void k_softmax(const short* __restrict__ sbuf,
                                                 short* __restrict__ abuf,
                                                 const float* __restrict__ qinv,
                                                 const float* __restrict__ kinv) {
  const int w = threadIdx.x >> 6, l = threadIdx.x & 63;
  const size_t row = (size_t)blockIdx.x * 4 + w;
  const short* p = sbuf + row * 1024 + l * 16;
  short* po = abuf + row * 1024 + l * 16;
  const float qi = qinv[row];
  const float* kv = kinv + ((row >> 12) << 10) + l * 16;
  float ki[16];
  *(float4*)&ki[0]  = *(const float4*)(kv);
  *(float4*)&ki[4]  = *(const float4*)(kv + 4);
  *(float4*)&ki[8]  = *(const float4*)(kv + 8);
  *(float4*)&ki[12] = *(const float4*)(kv + 12);
  short8 v0 = *(const short8*)p;
  short8 v1 = *(const short8*)(p + 8);
  float f[16];
  #pragma unroll
  for (int i = 0; i < 8; ++i) {
    f[i]     = b2f(v0[i]) * qi * ki[i];
    f[8 + i] = b2f(v1[i]) * qi * ki[8 + i];
  }
  float mx = f[0];
  #pragma unroll
  for (int i = 1; i < 16; ++i) mx = fmaxf(mx, f[i]);
  #pragma unroll
  for (int o = 32; o > 0; o >>= 1) mx = fmaxf(mx, __shfl_xor(mx, o, 64));
  float s = 0.f;
  #pragma unroll
  for (int i = 0; i < 16; ++i) { f[i] = __expf(f[i] - mx); s += f[i]; }
  #pragma unroll
  for (int o = 32; o > 0; o >>= 1) s += __shfl_xor(s, o, 64);
  const float inv = 1.f / s;
  #pragma unroll
  for (int i = 0; i < 8; ++i) { v0[i] = f2b(f[i] * inv); v1[i] = f2b(f[8 + i] * inv); }
  *(short8*)po = v0;
  *(short8*)(po + 8) = v1;
}

extern "C" void kernel_launch(void* const* d_in, const int* in_sizes, int n_in,
                              void* d_out, int out_size, void* d_ws, size_t ws_size,
                              hipStream_t stream)
{
  const float* hid = (const float*)d_in[0];
  const float* Wq  = (const float*)d_in[1];
  const float* bq  = (const float*)d_in[2];
  const float* Wk  = (const float*)d_in[3];
  const float* bk  = (const float*)d_in[4];
  const float* Wv  = (const float*)d_in[5];
  const float* bv  = (const float*)d_in[6];
  const float* Wo  = (const float*)d_in[7];
  const float* bo  = (const float*)d_in[8];

  char* ws = (char*)d_ws;
  short* hb  = (short*)(ws);                          // 64 MiB  bf16 hidden
  short* qb  = (short*)(ws + (size_t)67108864);       // 64 MiB  bf16 q raw; later attn (ab)
  short* knb = (short*)(ws + (size_t)134217728);      // 16 MiB  bf16 raw keys; later vwt
  short* mvb = (short*)(ws + (size_t)150994944);      // 16 MiB  bf16 V natural [b][m][h]
  short* wqb = (short*)(ws + (size_t)167772160);      // 2 MiB
  short* wkb = (short*)(ws + (size_t)169869312);      // 2 MiB  (contiguous with wvb: [Wk;Wv])
  short* wvb = (short*)(ws + (size_t)171966464);      // 2 MiB
  short* wob = (short*)(ws + (size_t)174063616);      // 4 MiB
  short* ab  = qb;                                    // attn (bf16) over dead qb
  short* vwt = knb;                                   // VWT[b][n][m] over dead knb
  short* sb  = (short*)d_out;                         // raw scores: d_out[0,64MiB)
  float* qinv = (float*)((char*)d_out + (size_t)67108864);           // 128 KiB
  float* kinv = (float*)((char*)d_out + (size_t)67108864 + 131072);  // 32 KiB
  float* out = (float*)d_out;

  // converts
  k_cvt<<<4096, 256, 0, stream>>>((const float4*)hid, (short4v*)hb, 33554432 / 4);
  k_cvtw<<<1280, 256, 0, stream>>>((const float4*)Wq, (const float4*)Wk,
                                   (const float4*)Wv, (const float4*)Wo,
                                   (short4v*)wqb, (short4v*)wkb, (short4v*)wvb, (short4v*)wob);

  // Q projection: qb = hb @ Wq^T + bq
  k_gemm256<0, 0, true, short><<<dim3(128, 4, 1), 512, 0, stream>>>(
      hb, nullptr, wqb, nullptr, bq, nullptr, qb, nullptr,
      1024, 1024, 1024, 0, 0, 0);
  // fused K+V projection (gathered rows): cols 0-1023 -> knb (+bk); 1024-2047 -> mvb (+bv)
  k_gemm256<1, 1, true, short><<<dim3(32, 8, 1), 512, 0, stream>>>(
      hb, nullptr, wkb, nullptr, bk, bv, knb, mvb,
      1024, 1024, 1024, 0, 0, 0);
  // row inverse norms (read-only)
  k_rownorm<<<8192, 256, 0, stream>>>(qb, qinv);
  k_rownorm<<<2048, 256, 0, stream>>>(knb, kinv);
  // scores on RAW q,k: sb[b][s][m] = q[b][s] . k[b][m]
  k_gemm256<0, 0, false, short><<<dim3(16, 4, 8), 512, 0, stream>>>(
      qb, nullptr, knb, nullptr, nullptr, nullptr, sb, nullptr,
      1024, 1024, 1024, (long)S_DIM * H_DIM, (long)M_DIM * H_DIM, (long)S_DIM * M_DIM);
  // VWT[b][n][m] = sum_h Wo[n][1024+h] * V[b][m][h]   (overwrites knb, dead after scores)
  k_gemm256<0, 0, false, short><<<dim3(4, 4, 8), 512, 0, stream>>>(
      wob + 1024, nullptr, mvb, nullptr, nullptr, nullptr, vwt, nullptr,
      1024, 2048, 1024, 0, (long)M_DIM * H_DIM, (long)M_DIM * H_DIM);
  // softmax rows with folded 1/(|q||k|) scaling: sb -> ab (over dead qb)
  k_softmax<<<8192, 256, 0, stream>>>(sb, ab, qinv, kinv);
  // output: out[r][n] = sum_k hb[r][k]*Wo[n][k] + sum_m ab[r][m]*VWT[b][n][m] + bo[n]
  k_gemm256<3, 0, true, float><<<dim3(128, 4, 1), 512, 0, stream>>>(
      hb, ab, wob, vwt, bo, nullptr, out, nullptr,
      2048, 1024, 2048, 0, 0, 0);
}

// Round 15
// 633.339 us; speedup vs baseline: 8.5820x; 8.5820x over previous
//
#include <hip/hip_runtime.h>
#include <hip/hip_bf16.h>
#include <type_traits>
#include <stdint.h>

#define AS1 __attribute__((address_space(1)))
#define AS3 __attribute__((address_space(3)))

typedef __attribute__((ext_vector_type(8))) short short8;
typedef __attribute__((ext_vector_type(4))) short short4v;
typedef __attribute__((ext_vector_type(4))) float floatx4;

#define B_DIM 8
#define S_DIM 4096
#define H_DIM 1024
#define M_DIM 1024

__device__ __forceinline__ float b2f(short s) {
  union { unsigned u; float f; } x;
  x.u = ((unsigned)(unsigned short)s) << 16;
  return x.f;
}
__device__ __forceinline__ short f2b(float f) {
  union { float f; unsigned u; } x;
  x.f = f;
  unsigned u = x.u;
  unsigned r = (u + 0x7fffu + ((u >> 16) & 1u)) >> 16;  // RNE
  return (short)(unsigned short)r;
}

// Clobber-free sync primitives (measured safe r7-r12).
#define SCHEDB() __builtin_amdgcn_sched_barrier(0)
#define VMCNT(N) asm volatile("s_waitcnt vmcnt(" #N ")")
#define BARRIER() do { SCHEDB(); __builtin_amdgcn_s_barrier(); SCHEDB(); } while (0)

__device__ __forceinline__ void async16(const void* g, void* l) {
  __builtin_amdgcn_global_load_lds((const AS1 void*)g, (AS3 void*)l, 16, 0, 0);
}

// ---------------- f32 -> bf16 convert (hidden states) ----------------
__global__ __launch_bounds__(256) void k_cvt(const float4* __restrict__ in,
                                             short4v* __restrict__ out, int n4) {
  const int stride = gridDim.x * 256;
  for (int i = blockIdx.x * 256 + threadIdx.x; i < n4; i += stride) {
    float4 v = in[i];
    short4v o = { f2b(v.x), f2b(v.y), f2b(v.z), f2b(v.w) };
    out[i] = o;
  }
}

// ---------------- all four weight converts in one launch ----------------
__global__ __launch_bounds__(256) void k_cvtw(const float4* __restrict__ Wq,
                                              const float4* __restrict__ Wk,
                                              const float4* __restrict__ Wv,
                                              const float4* __restrict__ Wo,
                                              short4v* __restrict__ wq,
                                              short4v* __restrict__ wk,
                                              short4v* __restrict__ wv,
                                              short4v* __restrict__ wo) {
  const int stride = gridDim.x * 256;
  for (int i = blockIdx.x * 256 + threadIdx.x; i < 1310720; i += stride) {
    const float4* src; short4v* dst; int j;
    if (i < 262144)      { src = Wq; dst = wq; j = i; }
    else if (i < 524288) { src = Wk; dst = wk; j = i - 262144; }
    else if (i < 786432) { src = Wv; dst = wv; j = i - 524288; }
    else                 { src = Wo; dst = wo; j = i - 786432; }
    float4 v = src[j];
    short4v o = { f2b(v.x), f2b(v.y), f2b(v.z), f2b(v.w) };
    dst[j] = o;
  }
}

// ============ 256x256 GEMM: A via LDS (64 KiB -> 2 blocks/CU), B via global->reg ============
// C[r][n] = sum_k A[r][k] * B[n][k] (+bias[n]).
// AMODE 0: A direct (row stride lda). 1: gathered rows (r -> b*4096 + (m*4095)/1023), K=1024.
//       2: A concat(A, A2), each row stride 1024, K=2048.
//       3: AMODE-2 A-side + B-side switch: k<1024 -> Bw (stride ldb); k>=1024 -> B2 + (row0>>12)*1M (stride 1024).
// EPI 0: C[row*1024 + n] (OutT). 1: KV natural split: col<1024 -> C; else Cv.
// A-stage rotation: A1,A3(t+1)@PH0 (2 calls, buf^1); A0,A2(t+2)@PH3 (2 calls, buf).
// B-reg loads: bfQ=bf(k1,t)@PH0; bfP=bf(k0,t+1)@PH2 (4 dwordx4 each, L2-resident panels).
// vmcnt ledger (queue [P3SA2][P0BL4][P0SA2][P2BL4]): VMCNT(8)@PH0, VMCNT(6)@PH2, VMCNT(6)@PH3.
// NOTE launch_bounds (512,2): r12's (512,4) capped VGPR at 64 -> acc[8][4] (128 regs) spilled,
// 6.6 GB scratch writes, 16x slowdown. (512,2) gives cap 256; 2 blocks/CU comes from 64 KiB LDS.
template<int AMODE, int EPI, bool HAS_BIAS, typename OutT>
__global__ __launch_bounds__(512, 2)
void k_gemm256(const short* __restrict__ A, const short* __restrict__ A2,
               const short* __restrict__ Bw, const short* __restrict__ B2,
               const float* __restrict__ bias, const float* __restrict__ bias2,
               OutT* __restrict__ C, short* __restrict__ Cv,
               int K, long lda, long ldb, long sA, long sB, long sC)
{
  // A only: [buf][256 rows][64 shorts]; row = 128B, XOR-swizzled by ((row&7)<<4). 64 KiB.
  __shared__ __align__(16) short lds[2][256 * 64];

  const int t512 = threadIdx.x;
  const int l = t512 & 63;
  const int w = t512 >> 6;            // wave 0..7
  const int wm = w >> 2, wn = w & 3;  // 2M x 4N wave grid
  const int z = blockIdx.z;

  // XCD-aware bijective chunk swizzle, col-fastest within chunk (A-panel reuse).
  const int gx = gridDim.x, gy = gridDim.y;
  const int orig = blockIdx.y * gx + blockIdx.x;
  const int nwg = gx * gy;
  int s = orig;
  if ((nwg & 7) == 0) {
    const int q8 = nwg >> 3;
    s = (orig & 7) * q8 + (orig >> 3);
  }
  const int row0 = (s / gy) * 256;
  const int col0 = (s % gy) * 256;

  const short* Az = A + (size_t)z * sA;
  const short* Bz = Bw + (size_t)z * sB;

  // staging geometry: one call = 64 rows x 128B = 8KB = 512 threads x 16B
  const int rloc = t512 >> 3;              // row within call, 0..63
  const int slot = t512 & 7;               // 16B slot
  const int sw = slot ^ (rloc & 7);        // pre-swizzled source slot
  const int nt = K >> 6;                   // K-tiles of 64

  // ds_read geometry (A)
  const int lr = l & 15;
  const int lkb = (l >> 4) << 4;           // 0,16,32,48 (bytes)
  const int aswz = (lr & 7) << 4;
  const int aRowByte = (wm * 128 + lr) * 128;

  // B per-lane reg-load bases (row = col0 + wn*64 + ni*16 + lr; 8 shorts at k-slot (l>>4)*8)
  const short* bb1;
  const short* bb2 = nullptr;
  if constexpr (AMODE == 3) {
    bb1 = Bw + (size_t)(col0 + wn * 64 + lr) * ldb + (l >> 4) * 8;
    bb2 = B2 + (size_t)(row0 >> 12) * 1048576 + (size_t)(col0 + wn * 64 + lr) * 1024 + (l >> 4) * 8;
  } else {
    bb1 = Bz + (size_t)(col0 + wn * 64 + lr) * ldb + (l >> 4) * 8;
  }

  auto srcA = [&](int R, int tile) -> const char* {
    if constexpr (AMODE == 2 || AMODE == 3) {
      const size_t row = (size_t)(row0 + R + rloc);
      if (tile < 16) return (const char*)A  + ((row * 1024 + (size_t)tile * 64) << 1) + (sw << 4);
      else           return (const char*)A2 + ((row * 1024 + (size_t)(tile - 16) * 64) << 1) + (sw << 4);
    } else if constexpr (AMODE == 1) {
      const int r = row0 + R + rloc;
      const unsigned m = (unsigned)(r & (M_DIM - 1));
      const int g = (r >> 10) * S_DIM + (int)((m * 4095u) / 1023u);
      return (const char*)A + (((size_t)g * H_DIM + (size_t)tile * 64) << 1) + (sw << 4);
    } else {
      return (const char*)Az + (((size_t)(row0 + R + rloc) * lda + (size_t)tile * 64) << 1) + (sw << 4);
    }
  };
  auto SA = [&](int buf, int R, int tile) {
    async16(srcA(R, tile), (char*)&lds[buf][0] + (size_t)(R + w * 8) * 128);
  };

  floatx4 acc[8][4];
  #pragma unroll
  for (int i = 0; i < 8; ++i)
    #pragma unroll
    for (int j = 0; j < 4; ++j)
      acc[i][j] = (floatx4){0.f, 0.f, 0.f, 0.f};

#define BL4(dst, tile, ks)                                                        \
  {                                                                               \
    if constexpr (AMODE == 3) {                                                   \
      if ((tile) < 16) {                                                          \
        _Pragma("unroll")                                                         \
        for (int ni = 0; ni < 4; ++ni)                                            \
          dst[ni] = *(const short8*)(bb1 + (size_t)ni * 16 * ldb +                \
                                     (size_t)(tile) * 64 + (ks) * 32);            \
      } else {                                                                    \
        _Pragma("unroll")                                                         \
        for (int ni = 0; ni < 4; ++ni)                                            \
          dst[ni] = *(const short8*)(bb2 + (size_t)ni * 16 * 1024 +               \
                                     (size_t)((tile) - 16) * 64 + (ks) * 32);     \
      }                                                                           \
    } else {                                                                      \
      _Pragma("unroll")                                                           \
      for (int ni = 0; ni < 4; ++ni)                                              \
        dst[ni] = *(const short8*)(bb1 + (size_t)ni * 16 * ldb +                  \
                                   (size_t)(tile) * 64 + (ks) * 32);              \
    }                                                                             \
  }
#define RD_A4(dst, ldsbase, Mh, ks)                                               \
  {                                                                               \
    _Pragma("unroll")                                                             \
    for (int mi = 0; mi < 4; ++mi)                                                \
      dst[mi] = *(const short8*)((ldsbase) + aRowByte + (Mh) * 8192 +             \
                                 mi * 2048 + ((((ks) * 64) + lkb) ^ aswz));       \
  }
#define MFMA16(Mh, av, bv)                                                        \
  {                                                                               \
    __builtin_amdgcn_s_setprio(1);                                                \
    _Pragma("unroll")                                                             \
    for (int mi = 0; mi < 4; ++mi)                                                \
      _Pragma("unroll")                                                           \
      for (int ni = 0; ni < 4; ++ni)                                              \
        acc[(Mh) * 4 + mi][ni] = __builtin_amdgcn_mfma_f32_16x16x32_bf16(         \
            av[mi], bv[ni], acc[(Mh) * 4 + mi][ni], 0, 0, 0);                     \
    __builtin_amdgcn_s_setprio(0);                                                \
  }

  short8 afX[4], afY[4], bfP[4], bfQ[4];

  // ---- prologue: tile0 full A (4) -> buf0; BL bfP(k0,t0); A0,A2 of t1 -> buf1 ----
  {
    const int t1 = (nt > 1) ? 1 : 0;
    SA(0, 0, 0); SA(0, 64, 0); SA(0, 128, 0); SA(0, 192, 0);
    BL4(bfP, 0, 0);
    SA(1, 0, t1); SA(1, 128, t1);
    SCHEDB();
    VMCNT(2);                      // tile0 A + bfP landed; keep A0A2(t1) pair in flight
    BARRIER();
    const char* L0A = (const char*)&lds[0][0];
    RD_A4(afX, L0A, 0, 0);         // q0 of t0
  }

  for (int t = 0; t < nt; ++t) {
    const int b = t & 1;
    const char* LA  = (const char*)&lds[b][0];
    const char* LA1 = (const char*)&lds[b ^ 1][0];
    const int tn  = (t + 1 < nt) ? t + 1 : nt - 1;
    const int tn2 = (t + 2 < nt) ? t + 2 : nt - 1;

    // ---- PH0: read q1 A; BL bfQ=bf(k1,t); stage A1,A3(t+1) -> buf^1 ----
    RD_A4(afY, LA, 1, 0);
    BL4(bfQ, t, 1);
    SA(b ^ 1, 64, tn); SA(b ^ 1, 192, tn);
    SCHEDB();
    VMCNT(8);                      // drains P2(t-1) BL: bfP ready for this MFMA
    BARRIER();
    MFMA16(0, afX, bfP);           // q0 = (Mh0,k0)
    BARRIER();

    // ---- PH1: read q2 A ----
    RD_A4(afX, LA, 0, 1);
    BARRIER();
    MFMA16(1, afY, bfP);           // q1 = (Mh1,k0)
    BARRIER();

    // ---- PH2: read q3 A; BL bfP=bf(k0,t+1) ----
    RD_A4(afY, LA, 1, 1);
    BL4(bfP, tn, 0);
    SCHEDB();
    VMCNT(6);                      // drains P0 BL (bfQ ready) + P3(t-1) SA (A0A2(t+1) in LDS)
    BARRIER();
    MFMA16(0, afX, bfQ);           // q2 = (Mh0,k1)
    BARRIER();

    // ---- PH3: read q0(t+1) from buf^1; stage A0,A2(t+2) -> buf ----
    RD_A4(afX, LA1, 0, 0);
    SA(b, 0, tn2); SA(b, 128, tn2);
    BARRIER();
    MFMA16(1, afY, bfQ);           // q3 = (Mh1,k1)
    SCHEDB();
    VMCNT(6);                      // drains P0 SA: A1,A3(t+1) in LDS for PH0(t+1) reads
    BARRIER();
  }
#undef RD_A4
#undef BL4
#undef MFMA16

  SCHEDB();
  VMCNT(0);  // drain leftover prefetches
  SCHEDB();

  OutT* Cz = C + (size_t)z * sC;
  const int rsub = (l >> 4) * 4;
  #pragma unroll
  for (int ni = 0; ni < 4; ++ni) {
    const int colg = col0 + wn * 64 + ni * 16 + lr;
    float bvv = 0.f;
    if constexpr (HAS_BIAS) {
      if constexpr (EPI == 1) bvv = (colg < 1024) ? bias[colg] : bias2[colg - 1024];
      else bvv = bias[colg];
    }
    #pragma unroll
    for (int m = 0; m < 8; ++m) {
      const int rg = row0 + wm * 128 + (m >> 2) * 64 + (m & 3) * 16 + rsub;
      #pragma unroll
      for (int j = 0; j < 4; ++j) {
        const float v = acc[m][ni][j] + bvv;
        const int rr = rg + j;
        if constexpr (EPI == 1) {
          if (colg < 1024) ((short*)C)[(size_t)rr * 1024 + colg] = f2b(v);
          else             Cv[(size_t)rr * 1024 + (colg - 1024)] = f2b(v);
        } else {
          const size_t o = (size_t)rr * 1024 + colg;
          if constexpr (std::is_same<OutT, float>::value) Cz[o] = v;
          else Cz[o] = f2b(v);
        }
      }
    }
  }
}

// ---------------- row inverse-L2-norm (read-only): inv[row] = 1/max(|x_row|,1e-12) ----------------
__global__ __launch_bounds__(256) void k_rownorm(const short* __restrict__ x,
                                                 float* __restrict__ inv) {
  const int w = threadIdx.x >> 6, l = threadIdx.x & 63;
  const size_t row = (size_t)blockIdx.x * 4 + w;
  const short* p = x + row * 1024 + l * 16;
  short8 v0 = *(const short8*)p;
  short8 v1 = *(const short8*)(p + 8);
  float ss = 0.f;
  #pragma unroll
  for (int i = 0; i < 8; ++i) {
    const float a = b2f(v0[i]), b = b2f(v1[i]);
    ss += a * a + b * b;
  }
  #pragma unroll
  for (int o = 32; o > 0; o >>= 1) ss += __shfl_xor(ss, o, 64);
  if (l == 0) inv[row] = 1.f / fmaxf(sqrtf(ss), 1e-12f);
}

// ---------------- softmax over rows of 1024 (bf16 sb -> bf16 ab) with norm folding ----------------
__global__ __launch_bounds__(256) void k_softmax(const short* __restrict__ sbuf,
                                                 short* __restrict__ abuf,
                                                 const float* __restrict__ qinv,
                                                 const float* __restrict__ kinv) {
  const int w = threadIdx.x >> 6, l = threadIdx.x & 63;
  const size_t row = (size_t)blockIdx.x * 4 + w;
  const short* p = sbuf + row * 1024 + l * 16;
  short* po = abuf + row * 1024 + l * 16;
  const float qi = qinv[row];
  const float* kv = kinv + ((row >> 12) << 10) + l * 16;
  float ki[16];
  *(float4*)&ki[0]  = *(const float4*)(kv);
  *(float4*)&ki[4]  = *(const float4*)(kv + 4);
  *(float4*)&ki[8]  = *(const float4*)(kv + 8);
  *(float4*)&ki[12] = *(const float4*)(kv + 12);
  short8 v0 = *(const short8*)p;
  short8 v1 = *(const short8*)(p + 8);
  float f[16];
  #pragma unroll
  for (int i = 0; i < 8; ++i) {
    f[i]     = b2f(v0[i]) * qi * ki[i];
    f[8 + i] = b2f(v1[i]) * qi * ki[8 + i];
  }
  float mx = f[0];
  #pragma unroll
  for (int i = 1; i < 16; ++i) mx = fmaxf(mx, f[i]);
  #pragma unroll
  for (int o = 32; o > 0; o >>= 1) mx = fmaxf(mx, __shfl_xor(mx, o, 64));
  float s = 0.f;
  #pragma unroll
  for (int i = 0; i < 16; ++i) { f[i] = __expf(f[i] - mx); s += f[i]; }
  #pragma unroll
  for (int o = 32; o > 0; o >>= 1) s += __shfl_xor(s, o, 64);
  const float inv = 1.f / s;
  #pragma unroll
  for (int i = 0; i < 8; ++i) { v0[i] = f2b(f[i] * inv); v1[i] = f2b(f[8 + i] * inv); }
  *(short8*)po = v0;
  *(short8*)(po + 8) = v1;
}

extern "C" void kernel_launch(void* const* d_in, const int* in_sizes, int n_in,
                              void* d_out, int out_size, void* d_ws, size_t ws_size,
                              hipStream_t stream)
{
  const float* hid = (const float*)d_in[0];
  const float* Wq  = (const float*)d_in[1];
  const float* bq  = (const float*)d_in[2];
  const float* Wk  = (const float*)d_in[3];
  const float* bk  = (const float*)d_in[4];
  const float* Wv  = (const float*)d_in[5];
  const float* bv  = (const float*)d_in[6];
  const float* Wo  = (const float*)d_in[7];
  const float* bo  = (const float*)d_in[8];

  char* ws = (char*)d_ws;
  short* hb  = (short*)(ws);                          // 64 MiB  bf16 hidden
  short* qb  = (short*)(ws + (size_t)67108864);       // 64 MiB  bf16 q raw; later attn (ab)
  short* knb = (short*)(ws + (size_t)134217728);      // 16 MiB  bf16 raw keys; later vwt
  short* mvb = (short*)(ws + (size_t)150994944);      // 16 MiB  bf16 V natural [b][m][h]
  short* wqb = (short*)(ws + (size_t)167772160);      // 2 MiB
  short* wkb = (short*)(ws + (size_t)169869312);      // 2 MiB  (contiguous with wvb: [Wk;Wv])
  short* wvb = (short*)(ws + (size_t)171966464);      // 2 MiB
  short* wob = (short*)(ws + (size_t)174063616);      // 4 MiB
  short* ab  = qb;                                    // attn (bf16) over dead qb
  short* vwt = knb;                                   // VWT[b][n][m] over dead knb
  short* sb  = (short*)d_out;                         // raw scores: d_out[0,64MiB)
  float* qinv = (float*)((char*)d_out + (size_t)67108864);           // 128 KiB
  float* kinv = (float*)((char*)d_out + (size_t)67108864 + 131072);  // 32 KiB
  float* out = (float*)d_out;

  // converts
  k_cvt<<<4096, 256, 0, stream>>>((const float4*)hid, (short4v*)hb, 33554432 / 4);
  k_cvtw<<<1280, 256, 0, stream>>>((const float4*)Wq, (const float4*)Wk,
                                   (const float4*)Wv, (const float4*)Wo,
                                   (short4v*)wqb, (short4v*)wkb, (short4v*)wvb, (short4v*)wob);

  // Q projection: qb = hb @ Wq^T + bq
  k_gemm256<0, 0, true, short><<<dim3(128, 4, 1), 512, 0, stream>>>(
      hb, nullptr, wqb, nullptr, bq, nullptr, qb, nullptr,
      1024, 1024, 1024, 0, 0, 0);
  // fused K+V projection (gathered rows): cols 0-1023 -> knb (+bk); 1024-2047 -> mvb (+bv)
  k_gemm256<1, 1, true, short><<<dim3(32, 8, 1), 512, 0, stream>>>(
      hb, nullptr, wkb, nullptr, bk, bv, knb, mvb,
      1024, 1024, 1024, 0, 0, 0);
  // row inverse norms (read-only)
  k_rownorm<<<8192, 256, 0, stream>>>(qb, qinv);
  k_rownorm<<<2048, 256, 0, stream>>>(knb, kinv);
  // scores on RAW q,k: sb[b][s][m] = q[b][s] . k[b][m]
  k_gemm256<0, 0, false, short><<<dim3(16, 4, 8), 512, 0, stream>>>(
      qb, nullptr, knb, nullptr, nullptr, nullptr, sb, nullptr,
      1024, 1024, 1024, (long)S_DIM * H_DIM, (long)M_DIM * H_DIM, (long)S_DIM * M_DIM);
  // VWT[b][n][m] = sum_h Wo[n][1024+h] * V[b][m][h]   (overwrites knb, dead after scores)
  k_gemm256<0, 0, false, short><<<dim3(4, 4, 8), 512, 0, stream>>>(
      wob + 1024, nullptr, mvb, nullptr, nullptr, nullptr, vwt, nullptr,
      1024, 2048, 1024, 0, (long)M_DIM * H_DIM, (long)M_DIM * H_DIM);
  // softmax rows with folded 1/(|q||k|) scaling: sb -> ab (over dead qb)
  k_softmax<<<8192, 256, 0, stream>>>(sb, ab, qinv, kinv);
  // output: out[r][n] = sum_k hb[r][k]*Wo[n][k] + sum_m ab[r][m]*VWT[b][n][m] + bo[n]
  k_gemm256<3, 0, true, float><<<dim3(128, 4, 1), 512, 0, stream>>>(
      hb, ab, wob, vwt, bo, nullptr, out, nullptr,
      2048, 1024, 2048, 0, 0, 0);
}

// Round 16
// 469.262 us; speedup vs baseline: 11.5826x; 1.3496x over previous
//
#include <hip/hip_runtime.h>
#include <hip/hip_bf16.h>
#include <type_traits>
#include <stdint.h>

#define AS1 __attribute__((address_space(1)))
#define AS3 __attribute__((address_space(3)))

typedef __attribute__((ext_vector_type(8))) short short8;
typedef __attribute__((ext_vector_type(4))) short short4v;
typedef __attribute__((ext_vector_type(4))) float floatx4;

#define B_DIM 8
#define S_DIM 4096
#define H_DIM 1024
#define M_DIM 1024

__device__ __forceinline__ float b2f(short s) {
  union { unsigned u; float f; } x;
  x.u = ((unsigned)(unsigned short)s) << 16;
  return x.f;
}
__device__ __forceinline__ short f2b(float f) {
  union { float f; unsigned u; } x;
  x.f = f;
  unsigned u = x.u;
  unsigned r = (u + 0x7fffu + ((u >> 16) & 1u)) >> 16;  // RNE
  return (short)(unsigned short)r;
}

// Clobber-free sync primitives (measured safe r7-r11).
#define SCHEDB() __builtin_amdgcn_sched_barrier(0)
#define VMCNT(N) asm volatile("s_waitcnt vmcnt(" #N ")")
#define BARRIER() do { SCHEDB(); __builtin_amdgcn_s_barrier(); SCHEDB(); } while (0)

__device__ __forceinline__ void async16(const void* g, void* l) {
  __builtin_amdgcn_global_load_lds((const AS1 void*)g, (AS3 void*)l, 16, 0, 0);
}

// ---------------- f32 -> bf16 convert (hidden states) ----------------
__global__ __launch_bounds__(256) void k_cvt(const float4* __restrict__ in,
                                             short4v* __restrict__ out, int n4) {
  const int stride = gridDim.x * 256;
  for (int i = blockIdx.x * 256 + threadIdx.x; i < n4; i += stride) {
    float4 v = in[i];
    short4v o = { f2b(v.x), f2b(v.y), f2b(v.z), f2b(v.w) };
    out[i] = o;
  }
}

// ---------------- all four weight converts in one launch ----------------
__global__ __launch_bounds__(256) void k_cvtw(const float4* __restrict__ Wq,
                                              const float4* __restrict__ Wk,
                                              const float4* __restrict__ Wv,
                                              const float4* __restrict__ Wo,
                                              short4v* __restrict__ wq,
                                              short4v* __restrict__ wk,
                                              short4v* __restrict__ wv,
                                              short4v* __restrict__ wo) {
  const int stride = gridDim.x * 256;
  for (int i = blockIdx.x * 256 + threadIdx.x; i < 1310720; i += stride) {
    const float4* src; short4v* dst; int j;
    if (i < 262144)      { src = Wq; dst = wq; j = i; }
    else if (i < 524288) { src = Wk; dst = wk; j = i - 262144; }
    else if (i < 786432) { src = Wv; dst = wv; j = i - 524288; }
    else                 { src = Wo; dst = wo; j = i - 786432; }
    float4 v = src[j];
    short4v o = { f2b(v.x), f2b(v.y), f2b(v.z), f2b(v.w) };
    dst[j] = o;
  }
}

// ============ 256x256 8-phase GEMM, fragment reads pipelined one phase ahead ============
// (r11 configuration — measured best: 470 us total, out-GEMM 143 us @ MfmaUtil 41%.)
// C[r][n] = sum_k A[r][k] * B[n][k] (+bias[n]).
// AMODE 0: A direct (row stride lda). 1: gathered rows (r -> b*4096 + (m*4095)/1023), K=1024.
//       2: A concat(A, A2), each row stride 1024, K=2048.
//       3: AMODE-2 A-side + B-side switch: k<1024 -> Bw (stride ldb); k>=1024 -> B2 + (row0>>12)*1M (stride 1024).
// EPI 0: C[row*1024 + n] (OutT). 1: KV natural split: col<1024 -> C[r*1024+col]; else Cv[r*1024+col-1024].
// Staging: P(t)@PH0 = {A1,A3 of t+1}(2); Q(t)@PH3 = {A0,A2,B0..B3 of t+2}(6).
// Drains: vmcnt(2)@PH2-end, vmcnt(6)@PH3-end. Fragment regs double-buffered (afX/afY, bf0/bf1).
// NOTE r12/r15 falsified: (512,4) bound spills acc (VGPR 64, 6.6 GB scratch, 16x slow);
// B-via-registers (64 KiB LDS) loses wm-wave B-sharing and goes latency-bound (633 us).
template<int AMODE, int EPI, bool HAS_BIAS, typename OutT>
__global__ __launch_bounds__(512, 2)
void k_gemm256(const short* __restrict__ A, const short* __restrict__ A2,
               const short* __restrict__ Bw, const short* __restrict__ B2,
               const float* __restrict__ bias, const float* __restrict__ bias2,
               OutT* __restrict__ C, short* __restrict__ Cv,
               int K, long lda, long ldb, long sA, long sB, long sC)
{
  // [buf][A=0/B=1][256 rows][64 shorts]; row = 128B, XOR-swizzled by ((row&7)<<4)
  __shared__ __align__(16) short lds[2][2][256 * 64];

  const int t512 = threadIdx.x;
  const int l = t512 & 63;
  const int w = t512 >> 6;            // wave 0..7
  const int wm = w >> 2, wn = w & 3;  // 2M x 4N wave grid
  const int z = blockIdx.z;

  // XCD-aware bijective chunk swizzle, col-fastest within chunk (A-panel reuse).
  const int gx = gridDim.x, gy = gridDim.y;
  const int orig = blockIdx.y * gx + blockIdx.x;
  const int nwg = gx * gy;
  int s = orig;
  if ((nwg & 7) == 0) {
    const int q8 = nwg >> 3;
    s = (orig & 7) * q8 + (orig >> 3);
  }
  const int row0 = (s / gy) * 256;
  const int col0 = (s % gy) * 256;

  const short* Az = A + (size_t)z * sA;
  const short* Bz = Bw + (size_t)z * sB;

  // staging geometry: one call = 64 rows x 128B = 8KB = 512 threads x 16B
  const int rloc = t512 >> 3;              // row within call, 0..63
  const int slot = t512 & 7;               // 16B slot
  const int sw = slot ^ (rloc & 7);        // pre-swizzled source slot
  const int nt = K >> 6;                   // K-tiles of 64

  // ds_read geometry
  const int lr = l & 15;
  const int lkb = (l >> 4) << 4;           // 0,16,32,48 (bytes)
  const int aswz = (lr & 7) << 4;
  const int aRowByte = (wm * 128 + lr) * 128;
  const int bRowByte = (wn * 64 + lr) * 128;

  auto srcA = [&](int R, int tile) -> const char* {
    if constexpr (AMODE == 2 || AMODE == 3) {
      const size_t row = (size_t)(row0 + R + rloc);
      if (tile < 16) return (const char*)A  + ((row * 1024 + (size_t)tile * 64) << 1) + (sw << 4);
      else           return (const char*)A2 + ((row * 1024 + (size_t)(tile - 16) * 64) << 1) + (sw << 4);
    } else if constexpr (AMODE == 1) {
      const int r = row0 + R + rloc;
      const unsigned m = (unsigned)(r & (M_DIM - 1));
      const int g = (r >> 10) * S_DIM + (int)((m * 4095u) / 1023u);
      return (const char*)A + (((size_t)g * H_DIM + (size_t)tile * 64) << 1) + (sw << 4);
    } else {
      return (const char*)Az + (((size_t)(row0 + R + rloc) * lda + (size_t)tile * 64) << 1) + (sw << 4);
    }
  };
  auto srcB = [&](int R, int tile) -> const char* {
    if constexpr (AMODE == 3) {
      const size_t row = (size_t)(col0 + R + rloc);
      if (tile < 16) return (const char*)Bw + ((row * ldb + (size_t)tile * 64) << 1) + (sw << 4);
      else           return (const char*)B2 + (((size_t)(row0 >> 12) * 1048576 +
                                                row * 1024 + (size_t)(tile - 16) * 64) << 1) + (sw << 4);
    } else {
      return (const char*)Bz + (((size_t)(col0 + R + rloc) * ldb + (size_t)tile * 64) << 1) + (sw << 4);
    }
  };
  auto SA = [&](int buf, int R, int tile) {
    async16(srcA(R, tile), (char*)&lds[buf][0][0] + (size_t)(R + w * 8) * 128);
  };
  auto SB = [&](int buf, int R, int tile) {
    async16(srcB(R, tile), (char*)&lds[buf][1][0] + (size_t)(R + w * 8) * 128);
  };

  floatx4 acc[8][4];
  #pragma unroll
  for (int i = 0; i < 8; ++i)
    #pragma unroll
    for (int j = 0; j < 4; ++j)
      acc[i][j] = (floatx4){0.f, 0.f, 0.f, 0.f};

  // ---- prologue: tile0 full (8) -> buf0; Qpre = {A0,A2,B0..B3 of t1} (6) -> buf1 ----
  {
    const int t1 = (nt > 1) ? 1 : 0;
    SA(0, 0, 0);  SA(0, 64, 0); SA(0, 128, 0); SA(0, 192, 0);
    SB(0, 0, 0);  SB(0, 64, 0); SB(0, 128, 0); SB(0, 192, 0);
    SA(1, 0, t1); SA(1, 128, t1);
    SB(1, 0, t1); SB(1, 64, t1); SB(1, 128, t1); SB(1, 192, t1);
    SCHEDB();
    VMCNT(6);
    BARRIER();
  }

#define RD_A4(dst, ldsbase, Mh, ks)                                               \
  {                                                                               \
    _Pragma("unroll")                                                             \
    for (int mi = 0; mi < 4; ++mi)                                                \
      dst[mi] = *(const short8*)((ldsbase) + aRowByte + (Mh) * 8192 +             \
                                 mi * 2048 + ((((ks) * 64) + lkb) ^ aswz));       \
  }
#define RD_B4(dst, ldsbase, ks)                                                   \
  {                                                                               \
    _Pragma("unroll")                                                             \
    for (int ni = 0; ni < 4; ++ni)                                                \
      dst[ni] = *(const short8*)((ldsbase) + bRowByte + ni * 2048 +               \
                                 ((((ks) * 64) + lkb) ^ aswz));                   \
  }
#define MFMA16(Mh, av, bv)                                                        \
  {                                                                               \
    __builtin_amdgcn_s_setprio(1);                                                \
    _Pragma("unroll")                                                             \
    for (int mi = 0; mi < 4; ++mi)                                                \
      _Pragma("unroll")                                                           \
      for (int ni = 0; ni < 4; ++ni)                                              \
        acc[(Mh) * 4 + mi][ni] = __builtin_amdgcn_mfma_f32_16x16x32_bf16(         \
            av[mi], bv[ni], acc[(Mh) * 4 + mi][ni], 0, 0, 0);                     \
    __builtin_amdgcn_s_setprio(0);                                                \
  }

  short8 afX[4], afY[4], bf0[4], bf1[4];

  // prologue-read: q0 of tile 0 (A Mh0-k0 -> afX, B k0 -> bf0) from buf0
  {
    const char* L0A = (const char*)&lds[0][0][0];
    const char* L0B = (const char*)&lds[0][1][0];
    RD_A4(afX, L0A, 0, 0);
    RD_B4(bf0, L0B, 0);
  }

  for (int t = 0; t < nt; ++t) {
    const int b = t & 1;
    const char* LA  = (const char*)&lds[b][0][0];
    const char* LB  = (const char*)&lds[b][1][0];
    const char* LA1 = (const char*)&lds[b ^ 1][0][0];
    const char* LB1 = (const char*)&lds[b ^ 1][1][0];
    const int tn  = (t + 1 < nt) ? t + 1 : nt - 1;
    const int tn2 = (t + 2 < nt) ? t + 2 : nt - 1;

    // ---- PH0: read q1 (A Mh1-k0 -> afY); stage P(t)={A1,A3 of t+1} -> buf^1 ----
    RD_A4(afY, LA, 1, 0);
    SA(b ^ 1, 64, tn); SA(b ^ 1, 192, tn);
    BARRIER();
    MFMA16(0, afX, bf0);          // q0 = (Mh0,k0)
    BARRIER();

    // ---- PH1: read q2 (A Mh0-k1 -> afX, B k1 -> bf1) ----
    RD_A4(afX, LA, 0, 1);
    RD_B4(bf1, LB, 1);
    BARRIER();
    MFMA16(1, afY, bf0);          // q1 = (Mh1,k0)
    BARRIER();

    // ---- PH2: read q3 (A Mh1-k1 -> afY) ----
    RD_A4(afY, LA, 1, 1);
    BARRIER();
    MFMA16(0, afX, bf1);          // q2 = (Mh0,k1)
    SCHEDB();
    VMCNT(2);                     // drain Q(t-1): tile t+1 A0,A2,B* landed
    BARRIER();

    // ---- PH3: read q0 of t+1 from buf^1 (afX, bf0); stage Q(t)={A0,A2,B* of t+2} -> buf ----
    RD_A4(afX, LA1, 0, 0);
    RD_B4(bf0, LB1, 0);
    SA(b, 0, tn2); SA(b, 128, tn2);
    SB(b, 0, tn2); SB(b, 64, tn2); SB(b, 128, tn2); SB(b, 192, tn2);
    BARRIER();
    MFMA16(1, afY, bf1);          // q3 = (Mh1,k1)
    SCHEDB();
    VMCNT(6);                     // drain P(t): tile t+1 A1,A3 landed
    BARRIER();
  }
#undef RD_A4
#undef RD_B4
#undef MFMA16

  SCHEDB();
  VMCNT(0);  // drain leftover prefetches (LDS unused from here)
  SCHEDB();

  OutT* Cz = C + (size_t)z * sC;
  const int rsub = (l >> 4) * 4;
  #pragma unroll
  for (int ni = 0; ni < 4; ++ni) {
    const int colg = col0 + wn * 64 + ni * 16 + lr;
    float bvv = 0.f;
    if constexpr (HAS_BIAS) {
      if constexpr (EPI == 1) bvv = (colg < 1024) ? bias[colg] : bias2[colg - 1024];
      else bvv = bias[colg];
    }
    #pragma unroll
    for (int m = 0; m < 8; ++m) {
      const int rg = row0 + wm * 128 + (m >> 2) * 64 + (m & 3) * 16 + rsub;
      #pragma unroll
      for (int j = 0; j < 4; ++j) {
        const float v = acc[m][ni][j] + bvv;
        const int rr = rg + j;
        if constexpr (EPI == 1) {
          if (colg < 1024) ((short*)C)[(size_t)rr * 1024 + colg] = f2b(v);
          else             Cv[(size_t)rr * 1024 + (colg - 1024)] = f2b(v);
        } else {
          const size_t o = (size_t)rr * 1024 + colg;
          if constexpr (std::is_same<OutT, float>::value) Cz[o] = v;
          else Cz[o] = f2b(v);
        }
      }
    }
  }
}

// ---------------- row inverse-L2-norm (read-only): inv[row] = 1/max(|x_row|,1e-12) ----------------
__global__ __launch_bounds__(256) void k_rownorm(const short* __restrict__ x,
                                                 float* __restrict__ inv) {
  const int w = threadIdx.x >> 6, l = threadIdx.x & 63;
  const size_t row = (size_t)blockIdx.x * 4 + w;
  const short* p = x + row * 1024 + l * 16;
  short8 v0 = *(const short8*)p;
  short8 v1 = *(const short8*)(p + 8);
  float ss = 0.f;
  #pragma unroll
  for (int i = 0; i < 8; ++i) {
    const float a = b2f(v0[i]), b = b2f(v1[i]);
    ss += a * a + b * b;
  }
  #pragma unroll
  for (int o = 32; o > 0; o >>= 1) ss += __shfl_xor(ss, o, 64);
  if (l == 0) inv[row] = 1.f / fmaxf(sqrtf(ss), 1e-12f);
}

// ---------------- softmax over rows of 1024 (bf16 sb -> bf16 ab) with norm folding ----------------
__global__ __launch_bounds__(256) void k_softmax(const short* __restrict__ sbuf,
                                                 short* __restrict__ abuf,
                                                 const float* __restrict__ qinv,
                                                 const float* __restrict__ kinv) {
  const int w = threadIdx.x >> 6, l = threadIdx.x & 63;
  const size_t row = (size_t)blockIdx.x * 4 + w;
  const short* p = sbuf + row * 1024 + l * 16;
  short* po = abuf + row * 1024 + l * 16;
  const float qi = qinv[row];
  const float* kv = kinv + ((row >> 12) << 10) + l * 16;
  float ki[16];
  *(float4*)&ki[0]  = *(const float4*)(kv);
  *(float4*)&ki[4]  = *(const float4*)(kv + 4);
  *(float4*)&ki[8]  = *(const float4*)(kv + 8);
  *(float4*)&ki[12] = *(const float4*)(kv + 12);
  short8 v0 = *(const short8*)p;
  short8 v1 = *(const short8*)(p + 8);
  float f[16];
  #pragma unroll
  for (int i = 0; i < 8; ++i) {
    f[i]     = b2f(v0[i]) * qi * ki[i];
    f[8 + i] = b2f(v1[i]) * qi * ki[8 + i];
  }
  float mx = f[0];
  #pragma unroll
  for (int i = 1; i < 16; ++i) mx = fmaxf(mx, f[i]);
  #pragma unroll
  for (int o = 32; o > 0; o >>= 1) mx = fmaxf(mx, __shfl_xor(mx, o, 64));
  float s = 0.f;
  #pragma unroll
  for (int i = 0; i < 16; ++i) { f[i] = __expf(f[i] - mx); s += f[i]; }
  #pragma unroll
  for (int o = 32; o > 0; o >>= 1) s += __shfl_xor(s, o, 64);
  const float inv = 1.f / s;
  #pragma unroll
  for (int i = 0; i < 8; ++i) { v0[i] = f2b(f[i] * inv); v1[i] = f2b(f[8 + i] * inv); }
  *(short8*)po = v0;
  *(short8*)(po + 8) = v1;
}

extern "C" void kernel_launch(void* const* d_in, const int* in_sizes, int n_in,
                              void* d_out, int out_size, void* d_ws, size_t ws_size,
                              hipStream_t stream)
{
  const float* hid = (const float*)d_in[0];
  const float* Wq  = (const float*)d_in[1];
  const float* bq  = (const float*)d_in[2];
  const float* Wk  = (const float*)d_in[3];
  const float* bk  = (const float*)d_in[4];
  const float* Wv  = (const float*)d_in[5];
  const float* bv  = (const float*)d_in[6];
  const float* Wo  = (const float*)d_in[7];
  const float* bo  = (const float*)d_in[8];

  char* ws = (char*)d_ws;
  short* hb  = (short*)(ws);                          // 64 MiB  bf16 hidden
  short* qb  = (short*)(ws + (size_t)67108864);       // 64 MiB  bf16 q raw; later attn (ab)
  short* knb = (short*)(ws + (size_t)134217728);      // 16 MiB  bf16 raw keys; later vwt
  short* mvb = (short*)(ws + (size_t)150994944);      // 16 MiB  bf16 V natural [b][m][h]
  short* wqb = (short*)(ws + (size_t)167772160);      // 2 MiB
  short* wkb = (short*)(ws + (size_t)169869312);      // 2 MiB  (contiguous with wvb: [Wk;Wv])
  short* wvb = (short*)(ws + (size_t)171966464);      // 2 MiB
  short* wob = (short*)(ws + (size_t)174063616);      // 4 MiB
  short* ab  = qb;                                    // attn (bf16) over dead qb
  short* vwt = knb;                                   // VWT[b][n][m] over dead knb
  short* sb  = (short*)d_out;                         // raw scores: d_out[0,64MiB)
  float* qinv = (float*)((char*)d_out + (size_t)67108864);           // 128 KiB
  float* kinv = (float*)((char*)d_out + (size_t)67108864 + 131072);  // 32 KiB
  float* out = (float*)d_out;

  // converts
  k_cvt<<<4096, 256, 0, stream>>>((const float4*)hid, (short4v*)hb, 33554432 / 4);
  k_cvtw<<<1280, 256, 0, stream>>>((const float4*)Wq, (const float4*)Wk,
                                   (const float4*)Wv, (const float4*)Wo,
                                   (short4v*)wqb, (short4v*)wkb, (short4v*)wvb, (short4v*)wob);

  // Q projection: qb = hb @ Wq^T + bq
  k_gemm256<0, 0, true, short><<<dim3(128, 4, 1), 512, 0, stream>>>(
      hb, nullptr, wqb, nullptr, bq, nullptr, qb, nullptr,
      1024, 1024, 1024, 0, 0, 0);
  // fused K+V projection (gathered rows): cols 0-1023 -> knb (+bk); 1024-2047 -> mvb (+bv)
  k_gemm256<1, 1, true, short><<<dim3(32, 8, 1), 512, 0, stream>>>(
      hb, nullptr, wkb, nullptr, bk, bv, knb, mvb,
      1024, 1024, 1024, 0, 0, 0);
  // row inverse norms (read-only)
  k_rownorm<<<8192, 256, 0, stream>>>(qb, qinv);
  k_rownorm<<<2048, 256, 0, stream>>>(knb, kinv);
  // scores on RAW q,k: sb[b][s][m] = q[b][s] . k[b][m]
  k_gemm256<0, 0, false, short><<<dim3(16, 4, 8), 512, 0, stream>>>(
      qb, nullptr, knb, nullptr, nullptr, nullptr, sb, nullptr,
      1024, 1024, 1024, (long)S_DIM * H_DIM, (long)M_DIM * H_DIM, (long)S_DIM * M_DIM);
  // VWT[b][n][m] = sum_h Wo[n][1024+h] * V[b][m][h]   (overwrites knb, dead after scores)
  k_gemm256<0, 0, false, short><<<dim3(4, 4, 8), 512, 0, stream>>>(
      wob + 1024, nullptr, mvb, nullptr, nullptr, nullptr, vwt, nullptr,
      1024, 2048, 1024, 0, (long)M_DIM * H_DIM, (long)M_DIM * H_DIM);
  // softmax rows with folded 1/(|q||k|) scaling: sb -> ab (over dead qb)
  k_softmax<<<8192, 256, 0, stream>>>(sb, ab, qinv, kinv);
  // output: out[r][n] = sum_k hb[r][k]*Wo[n][k] + sum_m ab[r][m]*VWT[b][n][m] + bo[n]
  k_gemm256<3, 0, true, float><<<dim3(128, 4, 1), 512, 0, stream>>>(
      hb, ab, wob, vwt, bo, nullptr, out, nullptr,
      2048, 1024, 2048, 0, 0, 0);
}

// Round 17
// 465.362 us; speedup vs baseline: 11.6797x; 1.0084x over previous
//
#include <hip/hip_runtime.h>
#include <hip/hip_bf16.h>
#include <type_traits>
#include <stdint.h>

#define AS1 __attribute__((address_space(1)))
#define AS3 __attribute__((address_space(3)))

typedef __attribute__((ext_vector_type(8))) short short8;
typedef __attribute__((ext_vector_type(4))) short short4v;
typedef __attribute__((ext_vector_type(16))) float floatx16;

#define B_DIM 8
#define S_DIM 4096
#define H_DIM 1024
#define M_DIM 1024

__device__ __forceinline__ float b2f(short s) {
  union { unsigned u; float f; } x;
  x.u = ((unsigned)(unsigned short)s) << 16;
  return x.f;
}
__device__ __forceinline__ short f2b(float f) {
  union { float f; unsigned u; } x;
  x.f = f;
  unsigned u = x.u;
  unsigned r = (u + 0x7fffu + ((u >> 16) & 1u)) >> 16;  // RNE
  return (short)(unsigned short)r;
}

// Clobber-free sync primitives (measured safe r7-r16).
#define SCHEDB() __builtin_amdgcn_sched_barrier(0)
#define VMCNT(N) asm volatile("s_waitcnt vmcnt(" #N ")")
#define BARRIER() do { SCHEDB(); __builtin_amdgcn_s_barrier(); SCHEDB(); } while (0)

__device__ __forceinline__ void async16(const void* g, void* l) {
  __builtin_amdgcn_global_load_lds((const AS1 void*)g, (AS3 void*)l, 16, 0, 0);
}

// ---------------- f32 -> bf16 convert (hidden states) ----------------
__global__ __launch_bounds__(256) void k_cvt(const float4* __restrict__ in,
                                             short4v* __restrict__ out, int n4) {
  const int stride = gridDim.x * 256;
  for (int i = blockIdx.x * 256 + threadIdx.x; i < n4; i += stride) {
    float4 v = in[i];
    short4v o = { f2b(v.x), f2b(v.y), f2b(v.z), f2b(v.w) };
    out[i] = o;
  }
}

// ---------------- all four weight converts in one launch ----------------
__global__ __launch_bounds__(256) void k_cvtw(const float4* __restrict__ Wq,
                                              const float4* __restrict__ Wk,
                                              const float4* __restrict__ Wv,
                                              const float4* __restrict__ Wo,
                                              short4v* __restrict__ wq,
                                              short4v* __restrict__ wk,
                                              short4v* __restrict__ wv,
                                              short4v* __restrict__ wo) {
  const int stride = gridDim.x * 256;
  for (int i = blockIdx.x * 256 + threadIdx.x; i < 1310720; i += stride) {
    const float4* src; short4v* dst; int j;
    if (i < 262144)      { src = Wq; dst = wq; j = i; }
    else if (i < 524288) { src = Wk; dst = wk; j = i - 262144; }
    else if (i < 786432) { src = Wv; dst = wv; j = i - 524288; }
    else                 { src = Wo; dst = wo; j = i - 786432; }
    float4 v = src[j];
    short4v o = { f2b(v.x), f2b(v.y), f2b(v.z), f2b(v.w) };
    dst[j] = o;
  }
}

// ============ 256x256 GEMM, 32x32x16 MFMA, fragment reads pipelined one phase ahead ============
// (r11 schedule/staging byte-identical; MFMA shape switched 16x16x32 -> 32x32x16:
//  17% fewer matrix-pipe cycles (m119: 8.07 vs 2x4.85 cyc), half the MFMA instructions.)
// C[r][n] = sum_k A[r][k] * B[n][k] (+bias[n]).
// AMODE 0: A direct (row stride lda). 1: gathered rows (r -> b*4096 + (m*4095)/1023), K=1024.
//       2: A concat(A, A2), each row stride 1024, K=2048.
//       3: AMODE-2 A-side + B-side switch: k<1024 -> Bw (stride ldb); k>=1024 -> B2 + (row0>>12)*1M (stride 1024).
// EPI 0: C[row*1024 + n] (OutT). 1: KV natural split: col<1024 -> C[r*1024+col]; else Cv[r*1024+col-1024].
// Staging: P(t)@PH0 = {A1,A3 of t+1}(2); Q(t)@PH3 = {A0,A2,B0..B3 of t+2}(6).
// Drains: vmcnt(2)@PH2-end, vmcnt(6)@PH3-end. Fragment regs double-buffered (afX/afY, bf0/bf1).
// Fragment layout (32x32x16, HW-verified m74/m101): A/B: lane holds row/col (l&31),
// k = (l>>5)*8 + j; C/D: col=l&31, row=(reg&3)+8*(reg>>2)+4*(l>>5).
// LDS read balance: slot (2ks+(l>>5))^(l&7) -> 8 accesses/bank uniform (minimum).
template<int AMODE, int EPI, bool HAS_BIAS, typename OutT>
__global__ __launch_bounds__(512, 2)
void k_gemm256(const short* __restrict__ A, const short* __restrict__ A2,
               const short* __restrict__ Bw, const short* __restrict__ B2,
               const float* __restrict__ bias, const float* __restrict__ bias2,
               OutT* __restrict__ C, short* __restrict__ Cv,
               int K, long lda, long ldb, long sA, long sB, long sC)
{
  // [buf][A=0/B=1][256 rows][64 shorts]; row = 128B, XOR-swizzled by ((row&7)<<4)
  __shared__ __align__(16) short lds[2][2][256 * 64];

  const int t512 = threadIdx.x;
  const int l = t512 & 63;
  const int w = t512 >> 6;            // wave 0..7
  const int wm = w >> 2, wn = w & 3;  // 2M x 4N wave grid
  const int z = blockIdx.z;

  // XCD-aware bijective chunk swizzle, col-fastest within chunk (A-panel reuse).
  const int gx = gridDim.x, gy = gridDim.y;
  const int orig = blockIdx.y * gx + blockIdx.x;
  const int nwg = gx * gy;
  int s = orig;
  if ((nwg & 7) == 0) {
    const int q8 = nwg >> 3;
    s = (orig & 7) * q8 + (orig >> 3);
  }
  const int row0 = (s / gy) * 256;
  const int col0 = (s % gy) * 256;

  const short* Az = A + (size_t)z * sA;
  const short* Bz = Bw + (size_t)z * sB;

  // staging geometry: one call = 64 rows x 128B = 8KB = 512 threads x 16B
  const int rloc = t512 >> 3;              // row within call, 0..63
  const int slot = t512 & 7;               // 16B slot
  const int sw = slot ^ (rloc & 7);        // pre-swizzled source slot
  const int nt = K >> 6;                   // K-tiles of 64

  // ds_read geometry (32x32x16 fragments)
  const int lc = l & 31;                   // fragment row/col
  const int kb16 = (l >> 5) << 4;          // 16B half within 32B k-step window
  const int aswz = (l & 7) << 4;           // XOR swizzle key ((row&7)<<4), row&7 == l&7
  const int aRowByte = (wm * 128 + lc) * 128;
  const int bRowByte = (wn * 64 + lc) * 128;

  auto srcA = [&](int R, int tile) -> const char* {
    if constexpr (AMODE == 2 || AMODE == 3) {
      const size_t row = (size_t)(row0 + R + rloc);
      if (tile < 16) return (const char*)A  + ((row * 1024 + (size_t)tile * 64) << 1) + (sw << 4);
      else           return (const char*)A2 + ((row * 1024 + (size_t)(tile - 16) * 64) << 1) + (sw << 4);
    } else if constexpr (AMODE == 1) {
      const int r = row0 + R + rloc;
      const unsigned m = (unsigned)(r & (M_DIM - 1));
      const int g = (r >> 10) * S_DIM + (int)((m * 4095u) / 1023u);
      return (const char*)A + (((size_t)g * H_DIM + (size_t)tile * 64) << 1) + (sw << 4);
    } else {
      return (const char*)Az + (((size_t)(row0 + R + rloc) * lda + (size_t)tile * 64) << 1) + (sw << 4);
    }
  };
  auto srcB = [&](int R, int tile) -> const char* {
    if constexpr (AMODE == 3) {
      const size_t row = (size_t)(col0 + R + rloc);
      if (tile < 16) return (const char*)Bw + ((row * ldb + (size_t)tile * 64) << 1) + (sw << 4);
      else           return (const char*)B2 + (((size_t)(row0 >> 12) * 1048576 +
                                                row * 1024 + (size_t)(tile - 16) * 64) << 1) + (sw << 4);
    } else {
      return (const char*)Bz + (((size_t)(col0 + R + rloc) * ldb + (size_t)tile * 64) << 1) + (sw << 4);
    }
  };
  auto SA = [&](int buf, int R, int tile) {
    async16(srcA(R, tile), (char*)&lds[buf][0][0] + (size_t)(R + w * 8) * 128);
  };
  auto SB = [&](int buf, int R, int tile) {
    async16(srcB(R, tile), (char*)&lds[buf][1][0] + (size_t)(R + w * 8) * 128);
  };

  floatx16 acc[4][2];
  {
    const floatx16 zz = {0.f,0.f,0.f,0.f,0.f,0.f,0.f,0.f,0.f,0.f,0.f,0.f,0.f,0.f,0.f,0.f};
    #pragma unroll
    for (int i = 0; i < 4; ++i)
      #pragma unroll
      for (int j = 0; j < 2; ++j)
        acc[i][j] = zz;
  }

  // ---- prologue: tile0 full (8) -> buf0; Qpre = {A0,A2,B0..B3 of t1} (6) -> buf1 ----
  {
    const int t1 = (nt > 1) ? 1 : 0;
    SA(0, 0, 0);  SA(0, 64, 0); SA(0, 128, 0); SA(0, 192, 0);
    SB(0, 0, 0);  SB(0, 64, 0); SB(0, 128, 0); SB(0, 192, 0);
    SA(1, 0, t1); SA(1, 128, t1);
    SB(1, 0, t1); SB(1, 64, t1); SB(1, 128, t1); SB(1, 192, t1);
    SCHEDB();
    VMCNT(6);
    BARRIER();
  }

// A quadrant (Mh rows-half, kh k-half): frags mi = fi_local*2 + ks_local
#define RD_A4(dst, ldsbase, Mh, kh)                                               \
  {                                                                               \
    _Pragma("unroll")                                                             \
    for (int mi = 0; mi < 4; ++mi) {                                              \
      const int fi = (Mh) * 2 + (mi >> 1);                                        \
      const int ks = (kh) * 2 + (mi & 1);                                         \
      dst[mi] = *(const short8*)((ldsbase) + aRowByte + fi * 4096 +               \
                                 ((ks * 32 + kb16) ^ aswz));                      \
    }                                                                             \
  }
// B half (kh): frags ni = fj*2 + ks_local
#define RD_B4(dst, ldsbase, kh)                                                   \
  {                                                                               \
    _Pragma("unroll")                                                             \
    for (int ni = 0; ni < 4; ++ni) {                                              \
      const int fj = ni >> 1;                                                     \
      const int ks = (kh) * 2 + (ni & 1);                                         \
      dst[ni] = *(const short8*)((ldsbase) + bRowByte + fj * 4096 +               \
                                 ((ks * 32 + kb16) ^ aswz));                      \
    }                                                                             \
  }
#define MFMA8(Mh, av, bv)                                                         \
  {                                                                               \
    __builtin_amdgcn_s_setprio(1);                                                \
    _Pragma("unroll")                                                             \
    for (int fi_ = 0; fi_ < 2; ++fi_)                                             \
      _Pragma("unroll")                                                           \
      for (int fj_ = 0; fj_ < 2; ++fj_)                                           \
        _Pragma("unroll")                                                         \
        for (int ks_ = 0; ks_ < 2; ++ks_)                                         \
          acc[(Mh) * 2 + fi_][fj_] = __builtin_amdgcn_mfma_f32_32x32x16_bf16(     \
              av[fi_ * 2 + ks_], bv[fj_ * 2 + ks_], acc[(Mh) * 2 + fi_][fj_],     \
              0, 0, 0);                                                           \
    __builtin_amdgcn_s_setprio(0);                                                \
  }

  short8 afX[4], afY[4], bf0[4], bf1[4];

  // prologue-read: q0 of tile 0 (A Mh0-kh0 -> afX, B kh0 -> bf0) from buf0
  {
    const char* L0A = (const char*)&lds[0][0][0];
    const char* L0B = (const char*)&lds[0][1][0];
    RD_A4(afX, L0A, 0, 0);
    RD_B4(bf0, L0B, 0);
  }

  for (int t = 0; t < nt; ++t) {
    const int b = t & 1;
    const char* LA  = (const char*)&lds[b][0][0];
    const char* LB  = (const char*)&lds[b][1][0];
    const char* LA1 = (const char*)&lds[b ^ 1][0][0];
    const char* LB1 = (const char*)&lds[b ^ 1][1][0];
    const int tn  = (t + 1 < nt) ? t + 1 : nt - 1;
    const int tn2 = (t + 2 < nt) ? t + 2 : nt - 1;

    // ---- PH0: read q1 (A Mh1-kh0 -> afY); stage P(t)={A1,A3 of t+1} -> buf^1 ----
    RD_A4(afY, LA, 1, 0);
    SA(b ^ 1, 64, tn); SA(b ^ 1, 192, tn);
    BARRIER();
    MFMA8(0, afX, bf0);           // q0 = (Mh0,kh0)
    BARRIER();

    // ---- PH1: read q2 (A Mh0-kh1 -> afX, B kh1 -> bf1) ----
    RD_A4(afX, LA, 0, 1);
    RD_B4(bf1, LB, 1);
    BARRIER();
    MFMA8(1, afY, bf0);           // q1 = (Mh1,kh0)
    BARRIER();

    // ---- PH2: read q3 (A Mh1-kh1 -> afY) ----
    RD_A4(afY, LA, 1, 1);
    BARRIER();
    MFMA8(0, afX, bf1);           // q2 = (Mh0,kh1)
    SCHEDB();
    VMCNT(2);                     // drain Q(t-1): tile t+1 A0,A2,B* landed
    BARRIER();

    // ---- PH3: read q0 of t+1 from buf^1 (afX, bf0); stage Q(t)={A0,A2,B* of t+2} -> buf ----
    RD_A4(afX, LA1, 0, 0);
    RD_B4(bf0, LB1, 0);
    SA(b, 0, tn2); SA(b, 128, tn2);
    SB(b, 0, tn2); SB(b, 64, tn2); SB(b, 128, tn2); SB(b, 192, tn2);
    BARRIER();
    MFMA8(1, afY, bf1);           // q3 = (Mh1,kh1)
    SCHEDB();
    VMCNT(6);                     // drain P(t): tile t+1 A1,A3 landed
    BARRIER();
  }
#undef RD_A4
#undef RD_B4
#undef MFMA8

  SCHEDB();
  VMCNT(0);  // drain leftover prefetches (LDS unused from here)
  SCHEDB();

  // Epilogue: C/D layout col=l&31, row=(reg&3)+8*(reg>>2)+4*(l>>5)  [m74/m101]
  OutT* Cz = C + (size_t)z * sC;
  const int rext = (l >> 5) << 2;
  #pragma unroll
  for (int fj = 0; fj < 2; ++fj) {
    const int colg = col0 + wn * 64 + fj * 32 + lc;
    float bvv = 0.f;
    if constexpr (HAS_BIAS) {
      if constexpr (EPI == 1) bvv = (colg < 1024) ? bias[colg] : bias2[colg - 1024];
      else bvv = bias[colg];
    }
    #pragma unroll
    for (int fi = 0; fi < 4; ++fi) {
      const int rbase = row0 + wm * 128 + fi * 32 + rext;
      #pragma unroll
      for (int i = 0; i < 16; ++i) {
        const float v = acc[fi][fj][i] + bvv;
        const int rr = rbase + (i & 3) + ((i >> 2) << 3);
        if constexpr (EPI == 1) {
          if (colg < 1024) ((short*)C)[(size_t)rr * 1024 + colg] = f2b(v);
          else             Cv[(size_t)rr * 1024 + (colg - 1024)] = f2b(v);
        } else {
          const size_t o = (size_t)rr * 1024 + colg;
          if constexpr (std::is_same<OutT, float>::value) Cz[o] = v;
          else Cz[o] = f2b(v);
        }
      }
    }
  }
}

// ---------------- row inverse-L2-norm (read-only): inv[row] = 1/max(|x_row|,1e-12) ----------------
__global__ __launch_bounds__(256) void k_rownorm(const short* __restrict__ x,
                                                 float* __restrict__ inv) {
  const int w = threadIdx.x >> 6, l = threadIdx.x & 63;
  const size_t row = (size_t)blockIdx.x * 4 + w;
  const short* p = x + row * 1024 + l * 16;
  short8 v0 = *(const short8*)p;
  short8 v1 = *(const short8*)(p + 8);
  float ss = 0.f;
  #pragma unroll
  for (int i = 0; i < 8; ++i) {
    const float a = b2f(v0[i]), b = b2f(v1[i]);
    ss += a * a + b * b;
  }
  #pragma unroll
  for (int o = 32; o > 0; o >>= 1) ss += __shfl_xor(ss, o, 64);
  if (l == 0) inv[row] = 1.f / fmaxf(sqrtf(ss), 1e-12f);
}

// ---------------- softmax over rows of 1024 (bf16 sb -> bf16 ab) with norm folding ----------------
__global__ __launch_bounds__(256) void k_softmax(const short* __restrict__ sbuf,
                                                 short* __restrict__ abuf,
                                                 const float* __restrict__ qinv,
                                                 const float* __restrict__ kinv) {
  const int w = threadIdx.x >> 6, l = threadIdx.x & 63;
  const size_t row = (size_t)blockIdx.x * 4 + w;
  const short* p = sbuf + row * 1024 + l * 16;
  short* po = abuf + row * 1024 + l * 16;
  const float qi = qinv[row];
  const float* kv = kinv + ((row >> 12) << 10) + l * 16;
  float ki[16];
  *(float4*)&ki[0]  = *(const float4*)(kv);
  *(float4*)&ki[4]  = *(const float4*)(kv + 4);
  *(float4*)&ki[8]  = *(const float4*)(kv + 8);
  *(float4*)&ki[12] = *(const float4*)(kv + 12);
  short8 v0 = *(const short8*)p;
  short8 v1 = *(const short8*)(p + 8);
  float f[16];
  #pragma unroll
  for (int i = 0; i < 8; ++i) {
    f[i]     = b2f(v0[i]) * qi * ki[i];
    f[8 + i] = b2f(v1[i]) * qi * ki[8 + i];
  }
  float mx = f[0];
  #pragma unroll
  for (int i = 1; i < 16; ++i) mx = fmaxf(mx, f[i]);
  #pragma unroll
  for (int o = 32; o > 0; o >>= 1) mx = fmaxf(mx, __shfl_xor(mx, o, 64));
  float s = 0.f;
  #pragma unroll
  for (int i = 0; i < 16; ++i) { f[i] = __expf(f[i] - mx); s += f[i]; }
  #pragma unroll
  for (int o = 32; o > 0; o >>= 1) s += __shfl_xor(s, o, 64);
  const float inv = 1.f / s;
  #pragma unroll
  for (int i = 0; i < 8; ++i) { v0[i] = f2b(f[i] * inv); v1[i] = f2b(f[8 + i] * inv); }
  *(short8*)po = v0;
  *(short8*)(po + 8) = v1;
}

extern "C" void kernel_launch(void* const* d_in, const int* in_sizes, int n_in,
                              void* d_out, int out_size, void* d_ws, size_t ws_size,
                              hipStream_t stream)
{
  const float* hid = (const float*)d_in[0];
  const float* Wq  = (const float*)d_in[1];
  const float* bq  = (const float*)d_in[2];
  const float* Wk  = (const float*)d_in[3];
  const float* bk  = (const float*)d_in[4];
  const float* Wv  = (const float*)d_in[5];
  const float* bv  = (const float*)d_in[6];
  const float* Wo  = (const float*)d_in[7];
  const float* bo  = (const float*)d_in[8];

  char* ws = (char*)d_ws;
  short* hb  = (short*)(ws);                          // 64 MiB  bf16 hidden
  short* qb  = (short*)(ws + (size_t)67108864);       // 64 MiB  bf16 q raw; later attn (ab)
  short* knb = (short*)(ws + (size_t)134217728);      // 16 MiB  bf16 raw keys; later vwt
  short* mvb = (short*)(ws + (size_t)150994944);      // 16 MiB  bf16 V natural [b][m][h]
  short* wqb = (short*)(ws + (size_t)167772160);      // 2 MiB
  short* wkb = (short*)(ws + (size_t)169869312);      // 2 MiB  (contiguous with wvb: [Wk;Wv])
  short* wvb = (short*)(ws + (size_t)171966464);      // 2 MiB
  short* wob = (short*)(ws + (size_t)174063616);      // 4 MiB
  short* ab  = qb;                                    // attn (bf16) over dead qb
  short* vwt = knb;                                   // VWT[b][n][m] over dead knb
  short* sb  = (short*)d_out;                         // raw scores: d_out[0,64MiB)
  float* qinv = (float*)((char*)d_out + (size_t)67108864);           // 128 KiB
  float* kinv = (float*)((char*)d_out + (size_t)67108864 + 131072);  // 32 KiB
  float* out = (float*)d_out;

  // converts
  k_cvt<<<4096, 256, 0, stream>>>((const float4*)hid, (short4v*)hb, 33554432 / 4);
  k_cvtw<<<1280, 256, 0, stream>>>((const float4*)Wq, (const float4*)Wk,
                                   (const float4*)Wv, (const float4*)Wo,
                                   (short4v*)wqb, (short4v*)wkb, (short4v*)wvb, (short4v*)wob);

  // Q projection: qb = hb @ Wq^T + bq
  k_gemm256<0, 0, true, short><<<dim3(128, 4, 1), 512, 0, stream>>>(
      hb, nullptr, wqb, nullptr, bq, nullptr, qb, nullptr,
      1024, 1024, 1024, 0, 0, 0);
  // fused K+V projection (gathered rows): cols 0-1023 -> knb (+bk); 1024-2047 -> mvb (+bv)
  k_gemm256<1, 1, true, short><<<dim3(32, 8, 1), 512, 0, stream>>>(
      hb, nullptr, wkb, nullptr, bk, bv, knb, mvb,
      1024, 1024, 1024, 0, 0, 0);
  // row inverse norms (read-only)
  k_rownorm<<<8192, 256, 0, stream>>>(qb, qinv);
  k_rownorm<<<2048, 256, 0, stream>>>(knb, kinv);
  // scores on RAW q,k: sb[b][s][m] = q[b][s] . k[b][m]
  k_gemm256<0, 0, false, short><<<dim3(16, 4, 8), 512, 0, stream>>>(
      qb, nullptr, knb, nullptr, nullptr, nullptr, sb, nullptr,
      1024, 1024, 1024, (long)S_DIM * H_DIM, (long)M_DIM * H_DIM, (long)S_DIM * M_DIM);
  // VWT[b][n][m] = sum_h Wo[n][1024+h] * V[b][m][h]   (overwrites knb, dead after scores)
  k_gemm256<0, 0, false, short><<<dim3(4, 4, 8), 512, 0, stream>>>(
      wob + 1024, nullptr, mvb, nullptr, nullptr, nullptr, vwt, nullptr,
      1024, 2048, 1024, 0, (long)M_DIM * H_DIM, (long)M_DIM * H_DIM);
  // softmax rows with folded 1/(|q||k|) scaling: sb -> ab (over dead qb)
  k_softmax<<<8192, 256, 0, stream>>>(sb, ab, qinv, kinv);
  // output: out[r][n] = sum_k hb[r][k]*Wo[n][k] + sum_m ab[r][m]*VWT[b][n][m] + bo[n]
  k_gemm256<3, 0, true, float><<<dim3(128, 4, 1), 512, 0, stream>>>(
      hb, ab, wob, vwt, bo, nullptr, out, nullptr,
      2048, 1024, 2048, 0, 0, 0);
}

// Round 18
// 456.604 us; speedup vs baseline: 11.9037x; 1.0192x over previous
//
#include <hip/hip_runtime.h>
#include <hip/hip_bf16.h>
#include <type_traits>
#include <stdint.h>

#define AS1 __attribute__((address_space(1)))
#define AS3 __attribute__((address_space(3)))

typedef __attribute__((ext_vector_type(8))) short short8;
typedef __attribute__((ext_vector_type(4))) short short4v;
typedef __attribute__((ext_vector_type(4))) float floatx4;
typedef __attribute__((ext_vector_type(16))) float floatx16;

#define B_DIM 8
#define S_DIM 4096
#define H_DIM 1024
#define M_DIM 1024

__device__ __forceinline__ float b2f(short s) {
  union { unsigned u; float f; } x;
  x.u = ((unsigned)(unsigned short)s) << 16;
  return x.f;
}
__device__ __forceinline__ short f2b(float f) {
  union { float f; unsigned u; } x;
  x.f = f;
  unsigned u = x.u;
  unsigned r = (u + 0x7fffu + ((u >> 16) & 1u)) >> 16;  // RNE
  return (short)(unsigned short)r;
}

// Clobber-free sync primitives (measured safe r7-r17).
#define SCHEDB() __builtin_amdgcn_sched_barrier(0)
#define VMCNT(N) asm volatile("s_waitcnt vmcnt(" #N ")")
#define BARRIER() do { SCHEDB(); __builtin_amdgcn_s_barrier(); SCHEDB(); } while (0)

__device__ __forceinline__ void async16(const void* g, void* l) {
  __builtin_amdgcn_global_load_lds((const AS1 void*)g, (AS3 void*)l, 16, 0, 0);
}

// ---------------- f32 -> bf16 convert (hidden states) ----------------
__global__ __launch_bounds__(256) void k_cvt(const float4* __restrict__ in,
                                             short4v* __restrict__ out, int n4) {
  const int stride = gridDim.x * 256;
  for (int i = blockIdx.x * 256 + threadIdx.x; i < n4; i += stride) {
    float4 v = in[i];
    short4v o = { f2b(v.x), f2b(v.y), f2b(v.z), f2b(v.w) };
    out[i] = o;
  }
}

// ---------------- all four weight converts in one launch ----------------
__global__ __launch_bounds__(256) void k_cvtw(const float4* __restrict__ Wq,
                                              const float4* __restrict__ Wk,
                                              const float4* __restrict__ Wv,
                                              const float4* __restrict__ Wo,
                                              short4v* __restrict__ wq,
                                              short4v* __restrict__ wk,
                                              short4v* __restrict__ wv,
                                              short4v* __restrict__ wo) {
  const int stride = gridDim.x * 256;
  for (int i = blockIdx.x * 256 + threadIdx.x; i < 1310720; i += stride) {
    const float4* src; short4v* dst; int j;
    if (i < 262144)      { src = Wq; dst = wq; j = i; }
    else if (i < 524288) { src = Wk; dst = wk; j = i - 262144; }
    else if (i < 786432) { src = Wv; dst = wv; j = i - 524288; }
    else                 { src = Wo; dst = wo; j = i - 786432; }
    float4 v = src[j];
    short4v o = { f2b(v.x), f2b(v.y), f2b(v.z), f2b(v.w) };
    dst[j] = o;
  }
}

// ============ Variant A: 256x256 GEMM, 16x16x32 MFMA (r16 body, byte-identical) ============
// Measured: out-GEMM 143 us, 0 LDS conflicts. Used for the K=2048 out-GEMM (AMODE 3).
template<int AMODE, int EPI, bool HAS_BIAS, typename OutT>
__global__ __launch_bounds__(512, 2)
void k_gemm16(const short* __restrict__ A, const short* __restrict__ A2,
              const short* __restrict__ Bw, const short* __restrict__ B2,
              const float* __restrict__ bias, const float* __restrict__ bias2,
              OutT* __restrict__ C, short* __restrict__ Cv,
              int K, long lda, long ldb, long sA, long sB, long sC)
{
  __shared__ __align__(16) short lds[2][2][256 * 64];

  const int t512 = threadIdx.x;
  const int l = t512 & 63;
  const int w = t512 >> 6;
  const int wm = w >> 2, wn = w & 3;
  const int z = blockIdx.z;

  const int gx = gridDim.x, gy = gridDim.y;
  const int orig = blockIdx.y * gx + blockIdx.x;
  const int nwg = gx * gy;
  int s = orig;
  if ((nwg & 7) == 0) {
    const int q8 = nwg >> 3;
    s = (orig & 7) * q8 + (orig >> 3);
  }
  const int row0 = (s / gy) * 256;
  const int col0 = (s % gy) * 256;

  const short* Az = A + (size_t)z * sA;
  const short* Bz = Bw + (size_t)z * sB;

  const int rloc = t512 >> 3;
  const int slot = t512 & 7;
  const int sw = slot ^ (rloc & 7);
  const int nt = K >> 6;

  const int lr = l & 15;
  const int lkb = (l >> 4) << 4;
  const int aswz = (lr & 7) << 4;
  const int aRowByte = (wm * 128 + lr) * 128;
  const int bRowByte = (wn * 64 + lr) * 128;

  auto srcA = [&](int R, int tile) -> const char* {
    if constexpr (AMODE == 2 || AMODE == 3) {
      const size_t row = (size_t)(row0 + R + rloc);
      if (tile < 16) return (const char*)A  + ((row * 1024 + (size_t)tile * 64) << 1) + (sw << 4);
      else           return (const char*)A2 + ((row * 1024 + (size_t)(tile - 16) * 64) << 1) + (sw << 4);
    } else if constexpr (AMODE == 1) {
      const int r = row0 + R + rloc;
      const unsigned m = (unsigned)(r & (M_DIM - 1));
      const int g = (r >> 10) * S_DIM + (int)((m * 4095u) / 1023u);
      return (const char*)A + (((size_t)g * H_DIM + (size_t)tile * 64) << 1) + (sw << 4);
    } else {
      return (const char*)Az + (((size_t)(row0 + R + rloc) * lda + (size_t)tile * 64) << 1) + (sw << 4);
    }
  };
  auto srcB = [&](int R, int tile) -> const char* {
    if constexpr (AMODE == 3) {
      const size_t row = (size_t)(col0 + R + rloc);
      if (tile < 16) return (const char*)Bw + ((row * ldb + (size_t)tile * 64) << 1) + (sw << 4);
      else           return (const char*)B2 + (((size_t)(row0 >> 12) * 1048576 +
                                                row * 1024 + (size_t)(tile - 16) * 64) << 1) + (sw << 4);
    } else {
      return (const char*)Bz + (((size_t)(col0 + R + rloc) * ldb + (size_t)tile * 64) << 1) + (sw << 4);
    }
  };
  auto SA = [&](int buf, int R, int tile) {
    async16(srcA(R, tile), (char*)&lds[buf][0][0] + (size_t)(R + w * 8) * 128);
  };
  auto SB = [&](int buf, int R, int tile) {
    async16(srcB(R, tile), (char*)&lds[buf][1][0] + (size_t)(R + w * 8) * 128);
  };

  floatx4 acc[8][4];
  #pragma unroll
  for (int i = 0; i < 8; ++i)
    #pragma unroll
    for (int j = 0; j < 4; ++j)
      acc[i][j] = (floatx4){0.f, 0.f, 0.f, 0.f};

  {
    const int t1 = (nt > 1) ? 1 : 0;
    SA(0, 0, 0);  SA(0, 64, 0); SA(0, 128, 0); SA(0, 192, 0);
    SB(0, 0, 0);  SB(0, 64, 0); SB(0, 128, 0); SB(0, 192, 0);
    SA(1, 0, t1); SA(1, 128, t1);
    SB(1, 0, t1); SB(1, 64, t1); SB(1, 128, t1); SB(1, 192, t1);
    SCHEDB();
    VMCNT(6);
    BARRIER();
  }

#define RD_A4(dst, ldsbase, Mh, ks)                                               \
  {                                                                               \
    _Pragma("unroll")                                                             \
    for (int mi = 0; mi < 4; ++mi)                                                \
      dst[mi] = *(const short8*)((ldsbase) + aRowByte + (Mh) * 8192 +             \
                                 mi * 2048 + ((((ks) * 64) + lkb) ^ aswz));       \
  }
#define RD_B4(dst, ldsbase, ks)                                                   \
  {                                                                               \
    _Pragma("unroll")                                                             \
    for (int ni = 0; ni < 4; ++ni)                                                \
      dst[ni] = *(const short8*)((ldsbase) + bRowByte + ni * 2048 +               \
                                 ((((ks) * 64) + lkb) ^ aswz));                   \
  }
#define MFMA16(Mh, av, bv)                                                        \
  {                                                                               \
    __builtin_amdgcn_s_setprio(1);                                                \
    _Pragma("unroll")                                                             \
    for (int mi = 0; mi < 4; ++mi)                                                \
      _Pragma("unroll")                                                           \
      for (int ni = 0; ni < 4; ++ni)                                              \
        acc[(Mh) * 4 + mi][ni] = __builtin_amdgcn_mfma_f32_16x16x32_bf16(         \
            av[mi], bv[ni], acc[(Mh) * 4 + mi][ni], 0, 0, 0);                     \
    __builtin_amdgcn_s_setprio(0);                                                \
  }

  short8 afX[4], afY[4], bf0[4], bf1[4];

  {
    const char* L0A = (const char*)&lds[0][0][0];
    const char* L0B = (const char*)&lds[0][1][0];
    RD_A4(afX, L0A, 0, 0);
    RD_B4(bf0, L0B, 0);
  }

  for (int t = 0; t < nt; ++t) {
    const int b = t & 1;
    const char* LA  = (const char*)&lds[b][0][0];
    const char* LB  = (const char*)&lds[b][1][0];
    const char* LA1 = (const char*)&lds[b ^ 1][0][0];
    const char* LB1 = (const char*)&lds[b ^ 1][1][0];
    const int tn  = (t + 1 < nt) ? t + 1 : nt - 1;
    const int tn2 = (t + 2 < nt) ? t + 2 : nt - 1;

    RD_A4(afY, LA, 1, 0);
    SA(b ^ 1, 64, tn); SA(b ^ 1, 192, tn);
    BARRIER();
    MFMA16(0, afX, bf0);
    BARRIER();

    RD_A4(afX, LA, 0, 1);
    RD_B4(bf1, LB, 1);
    BARRIER();
    MFMA16(1, afY, bf0);
    BARRIER();

    RD_A4(afY, LA, 1, 1);
    BARRIER();
    MFMA16(0, afX, bf1);
    SCHEDB();
    VMCNT(2);
    BARRIER();

    RD_A4(afX, LA1, 0, 0);
    RD_B4(bf0, LB1, 0);
    SA(b, 0, tn2); SA(b, 128, tn2);
    SB(b, 0, tn2); SB(b, 64, tn2); SB(b, 128, tn2); SB(b, 192, tn2);
    BARRIER();
    MFMA16(1, afY, bf1);
    SCHEDB();
    VMCNT(6);
    BARRIER();
  }
#undef RD_A4
#undef RD_B4
#undef MFMA16

  SCHEDB();
  VMCNT(0);
  SCHEDB();

  OutT* Cz = C + (size_t)z * sC;
  const int rsub = (l >> 4) * 4;
  #pragma unroll
  for (int ni = 0; ni < 4; ++ni) {
    const int colg = col0 + wn * 64 + ni * 16 + lr;
    float bvv = 0.f;
    if constexpr (HAS_BIAS) {
      if constexpr (EPI == 1) bvv = (colg < 1024) ? bias[colg] : bias2[colg - 1024];
      else bvv = bias[colg];
    }
    #pragma unroll
    for (int m = 0; m < 8; ++m) {
      const int rg = row0 + wm * 128 + (m >> 2) * 64 + (m & 3) * 16 + rsub;
      #pragma unroll
      for (int j = 0; j < 4; ++j) {
        const float v = acc[m][ni][j] + bvv;
        const int rr = rg + j;
        if constexpr (EPI == 1) {
          if (colg < 1024) ((short*)C)[(size_t)rr * 1024 + colg] = f2b(v);
          else             Cv[(size_t)rr * 1024 + (colg - 1024)] = f2b(v);
        } else {
          const size_t o = (size_t)rr * 1024 + colg;
          if constexpr (std::is_same<OutT, float>::value) Cz[o] = v;
          else Cz[o] = f2b(v);
        }
      }
    }
  }
}

// ============ Variant B: 256x256 GEMM, 32x32x16 MFMA (r17 body, byte-identical) ============
// Measured: K=1024 GEMMs collectively -13 us vs 16x16. Used for Qproj/KV/scores/VWT.
template<int AMODE, int EPI, bool HAS_BIAS, typename OutT>
__global__ __launch_bounds__(512, 2)
void k_gemm32(const short* __restrict__ A, const short* __restrict__ A2,
              const short* __restrict__ Bw, const short* __restrict__ B2,
              const float* __restrict__ bias, const float* __restrict__ bias2,
              OutT* __restrict__ C, short* __restrict__ Cv,
              int K, long lda, long ldb, long sA, long sB, long sC)
{
  __shared__ __align__(16) short lds[2][2][256 * 64];

  const int t512 = threadIdx.x;
  const int l = t512 & 63;
  const int w = t512 >> 6;
  const int wm = w >> 2, wn = w & 3;
  const int z = blockIdx.z;

  const int gx = gridDim.x, gy = gridDim.y;
  const int orig = blockIdx.y * gx + blockIdx.x;
  const int nwg = gx * gy;
  int s = orig;
  if ((nwg & 7) == 0) {
    const int q8 = nwg >> 3;
    s = (orig & 7) * q8 + (orig >> 3);
  }
  const int row0 = (s / gy) * 256;
  const int col0 = (s % gy) * 256;

  const short* Az = A + (size_t)z * sA;
  const short* Bz = Bw + (size_t)z * sB;

  const int rloc = t512 >> 3;
  const int slot = t512 & 7;
  const int sw = slot ^ (rloc & 7);
  const int nt = K >> 6;

  const int lc = l & 31;
  const int kb16 = (l >> 5) << 4;
  const int aswz = (l & 7) << 4;
  const int aRowByte = (wm * 128 + lc) * 128;
  const int bRowByte = (wn * 64 + lc) * 128;

  auto srcA = [&](int R, int tile) -> const char* {
    if constexpr (AMODE == 2 || AMODE == 3) {
      const size_t row = (size_t)(row0 + R + rloc);
      if (tile < 16) return (const char*)A  + ((row * 1024 + (size_t)tile * 64) << 1) + (sw << 4);
      else           return (const char*)A2 + ((row * 1024 + (size_t)(tile - 16) * 64) << 1) + (sw << 4);
    } else if constexpr (AMODE == 1) {
      const int r = row0 + R + rloc;
      const unsigned m = (unsigned)(r & (M_DIM - 1));
      const int g = (r >> 10) * S_DIM + (int)((m * 4095u) / 1023u);
      return (const char*)A + (((size_t)g * H_DIM + (size_t)tile * 64) << 1) + (sw << 4);
    } else {
      return (const char*)Az + (((size_t)(row0 + R + rloc) * lda + (size_t)tile * 64) << 1) + (sw << 4);
    }
  };
  auto srcB = [&](int R, int tile) -> const char* {
    if constexpr (AMODE == 3) {
      const size_t row = (size_t)(col0 + R + rloc);
      if (tile < 16) return (const char*)Bw + ((row * ldb + (size_t)tile * 64) << 1) + (sw << 4);
      else           return (const char*)B2 + (((size_t)(row0 >> 12) * 1048576 +
                                                row * 1024 + (size_t)(tile - 16) * 64) << 1) + (sw << 4);
    } else {
      return (const char*)Bz + (((size_t)(col0 + R + rloc) * ldb + (size_t)tile * 64) << 1) + (sw << 4);
    }
  };
  auto SA = [&](int buf, int R, int tile) {
    async16(srcA(R, tile), (char*)&lds[buf][0][0] + (size_t)(R + w * 8) * 128);
  };
  auto SB = [&](int buf, int R, int tile) {
    async16(srcB(R, tile), (char*)&lds[buf][1][0] + (size_t)(R + w * 8) * 128);
  };

  floatx16 acc[4][2];
  {
    const floatx16 zz = {0.f,0.f,0.f,0.f,0.f,0.f,0.f,0.f,0.f,0.f,0.f,0.f,0.f,0.f,0.f,0.f};
    #pragma unroll
    for (int i = 0; i < 4; ++i)
      #pragma unroll
      for (int j = 0; j < 2; ++j)
        acc[i][j] = zz;
  }

  {
    const int t1 = (nt > 1) ? 1 : 0;
    SA(0, 0, 0);  SA(0, 64, 0); SA(0, 128, 0); SA(0, 192, 0);
    SB(0, 0, 0);  SB(0, 64, 0); SB(0, 128, 0); SB(0, 192, 0);
    SA(1, 0, t1); SA(1, 128, t1);
    SB(1, 0, t1); SB(1, 64, t1); SB(1, 128, t1); SB(1, 192, t1);
    SCHEDB();
    VMCNT(6);
    BARRIER();
  }

#define RD_A4(dst, ldsbase, Mh, kh)                                               \
  {                                                                               \
    _Pragma("unroll")                                                             \
    for (int mi = 0; mi < 4; ++mi) {                                              \
      const int fi = (Mh) * 2 + (mi >> 1);                                        \
      const int ks = (kh) * 2 + (mi & 1);                                         \
      dst[mi] = *(const short8*)((ldsbase) + aRowByte + fi * 4096 +               \
                                 ((ks * 32 + kb16) ^ aswz));                      \
    }                                                                             \
  }
#define RD_B4(dst, ldsbase, kh)                                                   \
  {                                                                               \
    _Pragma("unroll")                                                             \
    for (int ni = 0; ni < 4; ++ni) {                                              \
      const int fj = ni >> 1;                                                     \
      const int ks = (kh) * 2 + (ni & 1);                                         \
      dst[ni] = *(const short8*)((ldsbase) + bRowByte + fj * 4096 +               \
                                 ((ks * 32 + kb16) ^ aswz));                      \
    }                                                                             \
  }
#define MFMA8(Mh, av, bv)                                                         \
  {                                                                               \
    __builtin_amdgcn_s_setprio(1);                                                \
    _Pragma("unroll")                                                             \
    for (int fi_ = 0; fi_ < 2; ++fi_)                                             \
      _Pragma("unroll")                                                           \
      for (int fj_ = 0; fj_ < 2; ++fj_)                                           \
        _Pragma("unroll")                                                         \
        for (int ks_ = 0; ks_ < 2; ++ks_)                                         \
          acc[(Mh) * 2 + fi_][fj_] = __builtin_amdgcn_mfma_f32_32x32x16_bf16(     \
              av[fi_ * 2 + ks_], bv[fj_ * 2 + ks_], acc[(Mh) * 2 + fi_][fj_],     \
              0, 0, 0);                                                           \
    __builtin_amdgcn_s_setprio(0);                                                \
  }

  short8 afX[4], afY[4], bf0[4], bf1[4];

  {
    const char* L0A = (const char*)&lds[0][0][0];
    const char* L0B = (const char*)&lds[0][1][0];
    RD_A4(afX, L0A, 0, 0);
    RD_B4(bf0, L0B, 0);
  }

  for (int t = 0; t < nt; ++t) {
    const int b = t & 1;
    const char* LA  = (const char*)&lds[b][0][0];
    const char* LB  = (const char*)&lds[b][1][0];
    const char* LA1 = (const char*)&lds[b ^ 1][0][0];
    const char* LB1 = (const char*)&lds[b ^ 1][1][0];
    const int tn  = (t + 1 < nt) ? t + 1 : nt - 1;
    const int tn2 = (t + 2 < nt) ? t + 2 : nt - 1;

    RD_A4(afY, LA, 1, 0);
    SA(b ^ 1, 64, tn); SA(b ^ 1, 192, tn);
    BARRIER();
    MFMA8(0, afX, bf0);
    BARRIER();

    RD_A4(afX, LA, 0, 1);
    RD_B4(bf1, LB, 1);
    BARRIER();
    MFMA8(1, afY, bf0);
    BARRIER();

    RD_A4(afY, LA, 1, 1);
    BARRIER();
    MFMA8(0, afX, bf1);
    SCHEDB();
    VMCNT(2);
    BARRIER();

    RD_A4(afX, LA1, 0, 0);
    RD_B4(bf0, LB1, 0);
    SA(b, 0, tn2); SA(b, 128, tn2);
    SB(b, 0, tn2); SB(b, 64, tn2); SB(b, 128, tn2); SB(b, 192, tn2);
    BARRIER();
    MFMA8(1, afY, bf1);
    SCHEDB();
    VMCNT(6);
    BARRIER();
  }
#undef RD_A4
#undef RD_B4
#undef MFMA8

  SCHEDB();
  VMCNT(0);
  SCHEDB();

  OutT* Cz = C + (size_t)z * sC;
  const int rext = (l >> 5) << 2;
  #pragma unroll
  for (int fj = 0; fj < 2; ++fj) {
    const int colg = col0 + wn * 64 + fj * 32 + lc;
    float bvv = 0.f;
    if constexpr (HAS_BIAS) {
      if constexpr (EPI == 1) bvv = (colg < 1024) ? bias[colg] : bias2[colg - 1024];
      else bvv = bias[colg];
    }
    #pragma unroll
    for (int fi = 0; fi < 4; ++fi) {
      const int rbase = row0 + wm * 128 + fi * 32 + rext;
      #pragma unroll
      for (int i = 0; i < 16; ++i) {
        const float v = acc[fi][fj][i] + bvv;
        const int rr = rbase + (i & 3) + ((i >> 2) << 3);
        if constexpr (EPI == 1) {
          if (colg < 1024) ((short*)C)[(size_t)rr * 1024 + colg] = f2b(v);
          else             Cv[(size_t)rr * 1024 + (colg - 1024)] = f2b(v);
        } else {
          const size_t o = (size_t)rr * 1024 + colg;
          if constexpr (std::is_same<OutT, float>::value) Cz[o] = v;
          else Cz[o] = f2b(v);
        }
      }
    }
  }
}

// ---------------- row inverse-L2-norm (read-only): inv[row] = 1/max(|x_row|,1e-12) ----------------
__global__ __launch_bounds__(256) void k_rownorm(const short* __restrict__ x,
                                                 float* __restrict__ inv) {
  const int w = threadIdx.x >> 6, l = threadIdx.x & 63;
  const size_t row = (size_t)blockIdx.x * 4 + w;
  const short* p = x + row * 1024 + l * 16;
  short8 v0 = *(const short8*)p;
  short8 v1 = *(const short8*)(p + 8);
  float ss = 0.f;
  #pragma unroll
  for (int i = 0; i < 8; ++i) {
    const float a = b2f(v0[i]), b = b2f(v1[i]);
    ss += a * a + b * b;
  }
  #pragma unroll
  for (int o = 32; o > 0; o >>= 1) ss += __shfl_xor(ss, o, 64);
  if (l == 0) inv[row] = 1.f / fmaxf(sqrtf(ss), 1e-12f);
}

// ---------------- softmax over rows of 1024 (bf16 sb -> bf16 ab) with norm folding ----------------
__global__ __launch_bounds__(256) void k_softmax(const short* __restrict__ sbuf,
                                                 short* __restrict__ abuf,
                                                 const float* __restrict__ qinv,
                                                 const float* __restrict__ kinv) {
  const int w = threadIdx.x >> 6, l = threadIdx.x & 63;
  const size_t row = (size_t)blockIdx.x * 4 + w;
  const short* p = sbuf + row * 1024 + l * 16;
  short* po = abuf + row * 1024 + l * 16;
  const float qi = qinv[row];
  const float* kv = kinv + ((row >> 12) << 10) + l * 16;
  float ki[16];
  *(float4*)&ki[0]  = *(const float4*)(kv);
  *(float4*)&ki[4]  = *(const float4*)(kv + 4);
  *(float4*)&ki[8]  = *(const float4*)(kv + 8);
  *(float4*)&ki[12] = *(const float4*)(kv + 12);
  short8 v0 = *(const short8*)p;
  short8 v1 = *(const short8*)(p + 8);
  float f[16];
  #pragma unroll
  for (int i = 0; i < 8; ++i) {
    f[i]     = b2f(v0[i]) * qi * ki[i];
    f[8 + i] = b2f(v1[i]) * qi * ki[8 + i];
  }
  float mx = f[0];
  #pragma unroll
  for (int i = 1; i < 16; ++i) mx = fmaxf(mx, f[i]);
  #pragma unroll
  for (int o = 32; o > 0; o >>= 1) mx = fmaxf(mx, __shfl_xor(mx, o, 64));
  float s = 0.f;
  #pragma unroll
  for (int i = 0; i < 16; ++i) { f[i] = __expf(f[i] - mx); s += f[i]; }
  #pragma unroll
  for (int o = 32; o > 0; o >>= 1) s += __shfl_xor(s, o, 64);
  const float inv = 1.f / s;
  #pragma unroll
  for (int i = 0; i < 8; ++i) { v0[i] = f2b(f[i] * inv); v1[i] = f2b(f[8 + i] * inv); }
  *(short8*)po = v0;
  *(short8*)(po + 8) = v1;
}

extern "C" void kernel_launch(void* const* d_in, const int* in_sizes, int n_in,
                              void* d_out, int out_size, void* d_ws, size_t ws_size,
                              hipStream_t stream)
{
  const float* hid = (const float*)d_in[0];
  const float* Wq  = (const float*)d_in[1];
  const float* bq  = (const float*)d_in[2];
  const float* Wk  = (const float*)d_in[3];
  const float* bk  = (const float*)d_in[4];
  const float* Wv  = (const float*)d_in[5];
  const float* bv  = (const float*)d_in[6];
  const float* Wo  = (const float*)d_in[7];
  const float* bo  = (const float*)d_in[8];

  char* ws = (char*)d_ws;
  short* hb  = (short*)(ws);                          // 64 MiB  bf16 hidden
  short* qb  = (short*)(ws + (size_t)67108864);       // 64 MiB  bf16 q raw; later attn (ab)
  short* knb = (short*)(ws + (size_t)134217728);      // 16 MiB  bf16 raw keys; later vwt
  short* mvb = (short*)(ws + (size_t)150994944);      // 16 MiB  bf16 V natural [b][m][h]
  short* wqb = (short*)(ws + (size_t)167772160);      // 2 MiB
  short* wkb = (short*)(ws + (size_t)169869312);      // 2 MiB
  short* wvb = (short*)(ws + (size_t)171966464);      // 2 MiB
  short* wob = (short*)(ws + (size_t)174063616);      // 4 MiB
  short* ab  = qb;                                    // attn (bf16) over dead qb
  short* vwt = knb;                                   // VWT[b][n][m] over dead knb
  short* sb  = (short*)d_out;                         // raw scores: d_out[0,64MiB)
  float* qinv = (float*)((char*)d_out + (size_t)67108864);           // 128 KiB
  float* kinv = (float*)((char*)d_out + (size_t)67108864 + 131072);  // 32 KiB
  float* out = (float*)d_out;

  // converts
  k_cvt<<<4096, 256, 0, stream>>>((const float4*)hid, (short4v*)hb, 33554432 / 4);
  k_cvtw<<<1280, 256, 0, stream>>>((const float4*)Wq, (const float4*)Wk,
                                   (const float4*)Wv, (const float4*)Wo,
                                   (short4v*)wqb, (short4v*)wkb, (short4v*)wvb, (short4v*)wob);

  // Q projection: qb = hb @ Wq^T + bq   (32x32 variant)
  k_gemm32<0, 0, true, short><<<dim3(128, 4, 1), 512, 0, stream>>>(
      hb, nullptr, wqb, nullptr, bq, nullptr, qb, nullptr,
      1024, 1024, 1024, 0, 0, 0);
  // fused K+V projection (gathered rows): cols 0-1023 -> knb (+bk); 1024-2047 -> mvb (+bv)
  k_gemm32<1, 1, true, short><<<dim3(32, 8, 1), 512, 0, stream>>>(
      hb, nullptr, wkb, nullptr, bk, bv, knb, mvb,
      1024, 1024, 1024, 0, 0, 0);
  // row inverse norms (read-only)
  k_rownorm<<<8192, 256, 0, stream>>>(qb, qinv);
  k_rownorm<<<2048, 256, 0, stream>>>(knb, kinv);
  // scores on RAW q,k: sb[b][s][m] = q[b][s] . k[b][m]
  k_gemm32<0, 0, false, short><<<dim3(16, 4, 8), 512, 0, stream>>>(
      qb, nullptr, knb, nullptr, nullptr, nullptr, sb, nullptr,
      1024, 1024, 1024, (long)S_DIM * H_DIM, (long)M_DIM * H_DIM, (long)S_DIM * M_DIM);
  // VWT[b][n][m] = sum_h Wo[n][1024+h] * V[b][m][h]   (overwrites knb, dead after scores)
  k_gemm32<0, 0, false, short><<<dim3(4, 4, 8), 512, 0, stream>>>(
      wob + 1024, nullptr, mvb, nullptr, nullptr, nullptr, vwt, nullptr,
      1024, 2048, 1024, 0, (long)M_DIM * H_DIM, (long)M_DIM * H_DIM);
  // softmax rows with folded 1/(|q||k|) scaling: sb -> ab (over dead qb)
  k_softmax<<<8192, 256, 0, stream>>>(sb, ab, qinv, kinv);
  // output: out[r][n] = sum_k hb[r][k]*Wo[n][k] + sum_m ab[r][m]*VWT[b][n][m] + bo[n]  (16x16 variant)
  k_gemm16<3, 0, true, float><<<dim3(128, 4, 1), 512, 0, stream>>>(
      hb, ab, wob, vwt, bo, nullptr, out, nullptr,
      2048, 1024, 2048, 0, 0, 0);
}

// Round 19
// 454.138 us; speedup vs baseline: 11.9684x; 1.0054x over previous
//
#include <hip/hip_runtime.h>
#include <hip/hip_bf16.h>
#include <type_traits>
#include <stdint.h>

#define AS1 __attribute__((address_space(1)))
#define AS3 __attribute__((address_space(3)))

typedef __attribute__((ext_vector_type(8))) short short8;
typedef __attribute__((ext_vector_type(4))) short short4v;
typedef __attribute__((ext_vector_type(4))) float floatx4;
typedef __attribute__((ext_vector_type(16))) float floatx16;

#define B_DIM 8
#define S_DIM 4096
#define H_DIM 1024
#define M_DIM 1024

__device__ __forceinline__ float b2f(short s) {
  union { unsigned u; float f; } x;
  x.u = ((unsigned)(unsigned short)s) << 16;
  return x.f;
}
__device__ __forceinline__ short f2b(float f) {
  union { float f; unsigned u; } x;
  x.f = f;
  unsigned u = x.u;
  unsigned r = (u + 0x7fffu + ((u >> 16) & 1u)) >> 16;  // RNE
  return (short)(unsigned short)r;
}

// Clobber-free sync primitives (measured safe r7-r18).
#define SCHEDB() __builtin_amdgcn_sched_barrier(0)
#define VMCNT(N) asm volatile("s_waitcnt vmcnt(" #N ")")
#define BARRIER() do { SCHEDB(); __builtin_amdgcn_s_barrier(); SCHEDB(); } while (0)

__device__ __forceinline__ void async16(const void* g, void* l) {
  __builtin_amdgcn_global_load_lds((const AS1 void*)g, (AS3 void*)l, 16, 0, 0);
}

// ---------------- all f32->bf16 converts in ONE launch (hidden + 4 weights) ----------------
__global__ __launch_bounds__(256) void k_cvtall(const float4* __restrict__ hid,
                                                const float4* __restrict__ Wq,
                                                const float4* __restrict__ Wk,
                                                const float4* __restrict__ Wv,
                                                const float4* __restrict__ Wo,
                                                short4v* __restrict__ hb,
                                                short4v* __restrict__ wq,
                                                short4v* __restrict__ wk,
                                                short4v* __restrict__ wv,
                                                short4v* __restrict__ wo) {
  const int stride = gridDim.x * 256;
  for (int i = blockIdx.x * 256 + threadIdx.x; i < 9699328; i += stride) {
    const float4* src; short4v* dst; int j;
    if (i < 8388608)      { src = hid; dst = hb; j = i; }
    else if (i < 8650752) { src = Wq;  dst = wq; j = i - 8388608; }
    else if (i < 8912896) { src = Wk;  dst = wk; j = i - 8650752; }
    else if (i < 9175040) { src = Wv;  dst = wv; j = i - 8912896; }
    else                  { src = Wo;  dst = wo; j = i - 9175040; }
    float4 v = src[j];
    short4v o = { f2b(v.x), f2b(v.y), f2b(v.z), f2b(v.w) };
    dst[j] = o;
  }
}

// ============ Variant A: 256x256 GEMM, 16x16x32 MFMA (r16 body, byte-identical) ============
// Measured: out-GEMM 143 us, 0 LDS conflicts. Used for the K=2048 out-GEMM (AMODE 3).
template<int AMODE, int EPI, bool HAS_BIAS, typename OutT>
__global__ __launch_bounds__(512, 2)
void k_gemm16(const short* __restrict__ A, const short* __restrict__ A2,
              const short* __restrict__ Bw, const short* __restrict__ B2,
              const float* __restrict__ bias, const float* __restrict__ bias2,
              OutT* __restrict__ C, short* __restrict__ Cv,
              int K, long lda, long ldb, long sA, long sB, long sC)
{
  __shared__ __align__(16) short lds[2][2][256 * 64];

  const int t512 = threadIdx.x;
  const int l = t512 & 63;
  const int w = t512 >> 6;
  const int wm = w >> 2, wn = w & 3;
  const int z = blockIdx.z;

  const int gx = gridDim.x, gy = gridDim.y;
  const int orig = blockIdx.y * gx + blockIdx.x;
  const int nwg = gx * gy;
  int s = orig;
  if ((nwg & 7) == 0) {
    const int q8 = nwg >> 3;
    s = (orig & 7) * q8 + (orig >> 3);
  }
  const int row0 = (s / gy) * 256;
  const int col0 = (s % gy) * 256;

  const short* Az = A + (size_t)z * sA;
  const short* Bz = Bw + (size_t)z * sB;

  const int rloc = t512 >> 3;
  const int slot = t512 & 7;
  const int sw = slot ^ (rloc & 7);
  const int nt = K >> 6;

  const int lr = l & 15;
  const int lkb = (l >> 4) << 4;
  const int aswz = (lr & 7) << 4;
  const int aRowByte = (wm * 128 + lr) * 128;
  const int bRowByte = (wn * 64 + lr) * 128;

  auto srcA = [&](int R, int tile) -> const char* {
    if constexpr (AMODE == 2 || AMODE == 3) {
      const size_t row = (size_t)(row0 + R + rloc);
      if (tile < 16) return (const char*)A  + ((row * 1024 + (size_t)tile * 64) << 1) + (sw << 4);
      else           return (const char*)A2 + ((row * 1024 + (size_t)(tile - 16) * 64) << 1) + (sw << 4);
    } else if constexpr (AMODE == 1) {
      const int r = row0 + R + rloc;
      const unsigned m = (unsigned)(r & (M_DIM - 1));
      const int g = (r >> 10) * S_DIM + (int)((m * 4095u) / 1023u);
      return (const char*)A + (((size_t)g * H_DIM + (size_t)tile * 64) << 1) + (sw << 4);
    } else {
      return (const char*)Az + (((size_t)(row0 + R + rloc) * lda + (size_t)tile * 64) << 1) + (sw << 4);
    }
  };
  auto srcB = [&](int R, int tile) -> const char* {
    if constexpr (AMODE == 3) {
      const size_t row = (size_t)(col0 + R + rloc);
      if (tile < 16) return (const char*)Bw + ((row * ldb + (size_t)tile * 64) << 1) + (sw << 4);
      else           return (const char*)B2 + (((size_t)(row0 >> 12) * 1048576 +
                                                row * 1024 + (size_t)(tile - 16) * 64) << 1) + (sw << 4);
    } else {
      return (const char*)Bz + (((size_t)(col0 + R + rloc) * ldb + (size_t)tile * 64) << 1) + (sw << 4);
    }
  };
  auto SA = [&](int buf, int R, int tile) {
    async16(srcA(R, tile), (char*)&lds[buf][0][0] + (size_t)(R + w * 8) * 128);
  };
  auto SB = [&](int buf, int R, int tile) {
    async16(srcB(R, tile), (char*)&lds[buf][1][0] + (size_t)(R + w * 8) * 128);
  };

  floatx4 acc[8][4];
  #pragma unroll
  for (int i = 0; i < 8; ++i)
    #pragma unroll
    for (int j = 0; j < 4; ++j)
      acc[i][j] = (floatx4){0.f, 0.f, 0.f, 0.f};

  {
    const int t1 = (nt > 1) ? 1 : 0;
    SA(0, 0, 0);  SA(0, 64, 0); SA(0, 128, 0); SA(0, 192, 0);
    SB(0, 0, 0);  SB(0, 64, 0); SB(0, 128, 0); SB(0, 192, 0);
    SA(1, 0, t1); SA(1, 128, t1);
    SB(1, 0, t1); SB(1, 64, t1); SB(1, 128, t1); SB(1, 192, t1);
    SCHEDB();
    VMCNT(6);
    BARRIER();
  }

#define RD_A4(dst, ldsbase, Mh, ks)                                               \
  {                                                                               \
    _Pragma("unroll")                                                             \
    for (int mi = 0; mi < 4; ++mi)                                                \
      dst[mi] = *(const short8*)((ldsbase) + aRowByte + (Mh) * 8192 +             \
                                 mi * 2048 + ((((ks) * 64) + lkb) ^ aswz));       \
  }
#define RD_B4(dst, ldsbase, ks)                                                   \
  {                                                                               \
    _Pragma("unroll")                                                             \
    for (int ni = 0; ni < 4; ++ni)                                                \
      dst[ni] = *(const short8*)((ldsbase) + bRowByte + ni * 2048 +               \
                                 ((((ks) * 64) + lkb) ^ aswz));                   \
  }
#define MFMA16(Mh, av, bv)                                                        \
  {                                                                               \
    __builtin_amdgcn_s_setprio(1);                                                \
    _Pragma("unroll")                                                             \
    for (int mi = 0; mi < 4; ++mi)                                                \
      _Pragma("unroll")                                                           \
      for (int ni = 0; ni < 4; ++ni)                                              \
        acc[(Mh) * 4 + mi][ni] = __builtin_amdgcn_mfma_f32_16x16x32_bf16(         \
            av[mi], bv[ni], acc[(Mh) * 4 + mi][ni], 0, 0, 0);                     \
    __builtin_amdgcn_s_setprio(0);                                                \
  }

  short8 afX[4], afY[4], bf0[4], bf1[4];

  {
    const char* L0A = (const char*)&lds[0][0][0];
    const char* L0B = (const char*)&lds[0][1][0];
    RD_A4(afX, L0A, 0, 0);
    RD_B4(bf0, L0B, 0);
  }

  for (int t = 0; t < nt; ++t) {
    const int b = t & 1;
    const char* LA  = (const char*)&lds[b][0][0];
    const char* LB  = (const char*)&lds[b][1][0];
    const char* LA1 = (const char*)&lds[b ^ 1][0][0];
    const char* LB1 = (const char*)&lds[b ^ 1][1][0];
    const int tn  = (t + 1 < nt) ? t + 1 : nt - 1;
    const int tn2 = (t + 2 < nt) ? t + 2 : nt - 1;

    RD_A4(afY, LA, 1, 0);
    SA(b ^ 1, 64, tn); SA(b ^ 1, 192, tn);
    BARRIER();
    MFMA16(0, afX, bf0);
    BARRIER();

    RD_A4(afX, LA, 0, 1);
    RD_B4(bf1, LB, 1);
    BARRIER();
    MFMA16(1, afY, bf0);
    BARRIER();

    RD_A4(afY, LA, 1, 1);
    BARRIER();
    MFMA16(0, afX, bf1);
    SCHEDB();
    VMCNT(2);
    BARRIER();

    RD_A4(afX, LA1, 0, 0);
    RD_B4(bf0, LB1, 0);
    SA(b, 0, tn2); SA(b, 128, tn2);
    SB(b, 0, tn2); SB(b, 64, tn2); SB(b, 128, tn2); SB(b, 192, tn2);
    BARRIER();
    MFMA16(1, afY, bf1);
    SCHEDB();
    VMCNT(6);
    BARRIER();
  }
#undef RD_A4
#undef RD_B4
#undef MFMA16

  SCHEDB();
  VMCNT(0);
  SCHEDB();

  OutT* Cz = C + (size_t)z * sC;
  const int rsub = (l >> 4) * 4;
  #pragma unroll
  for (int ni = 0; ni < 4; ++ni) {
    const int colg = col0 + wn * 64 + ni * 16 + lr;
    float bvv = 0.f;
    if constexpr (HAS_BIAS) {
      if constexpr (EPI == 1) bvv = (colg < 1024) ? bias[colg] : bias2[colg - 1024];
      else bvv = bias[colg];
    }
    #pragma unroll
    for (int m = 0; m < 8; ++m) {
      const int rg = row0 + wm * 128 + (m >> 2) * 64 + (m & 3) * 16 + rsub;
      #pragma unroll
      for (int j = 0; j < 4; ++j) {
        const float v = acc[m][ni][j] + bvv;
        const int rr = rg + j;
        if constexpr (EPI == 1) {
          if (colg < 1024) ((short*)C)[(size_t)rr * 1024 + colg] = f2b(v);
          else             Cv[(size_t)rr * 1024 + (colg - 1024)] = f2b(v);
        } else {
          const size_t o = (size_t)rr * 1024 + colg;
          if constexpr (std::is_same<OutT, float>::value) Cz[o] = v;
          else Cz[o] = f2b(v);
        }
      }
    }
  }
}

// ============ Variant B: 256x256 GEMM, 32x32x16 MFMA (r17 body, byte-identical) ============
// Measured: K=1024 GEMMs collectively -13 us vs 16x16. Used for Qproj/KV/scores/VWT.
template<int AMODE, int EPI, bool HAS_BIAS, typename OutT>
__global__ __launch_bounds__(512, 2)
void k_gemm32(const short* __restrict__ A, const short* __restrict__ A2,
              const short* __restrict__ Bw, const short* __restrict__ B2,
              const float* __restrict__ bias, const float* __restrict__ bias2,
              OutT* __restrict__ C, short* __restrict__ Cv,
              int K, long lda, long ldb, long sA, long sB, long sC)
{
  __shared__ __align__(16) short lds[2][2][256 * 64];

  const int t512 = threadIdx.x;
  const int l = t512 & 63;
  const int w = t512 >> 6;
  const int wm = w >> 2, wn = w & 3;
  const int z = blockIdx.z;

  const int gx = gridDim.x, gy = gridDim.y;
  const int orig = blockIdx.y * gx + blockIdx.x;
  const int nwg = gx * gy;
  int s = orig;
  if ((nwg & 7) == 0) {
    const int q8 = nwg >> 3;
    s = (orig & 7) * q8 + (orig >> 3);
  }
  const int row0 = (s / gy) * 256;
  const int col0 = (s % gy) * 256;

  const short* Az = A + (size_t)z * sA;
  const short* Bz = Bw + (size_t)z * sB;

  const int rloc = t512 >> 3;
  const int slot = t512 & 7;
  const int sw = slot ^ (rloc & 7);
  const int nt = K >> 6;

  const int lc = l & 31;
  const int kb16 = (l >> 5) << 4;
  const int aswz = (l & 7) << 4;
  const int aRowByte = (wm * 128 + lc) * 128;
  const int bRowByte = (wn * 64 + lc) * 128;

  auto srcA = [&](int R, int tile) -> const char* {
    if constexpr (AMODE == 2 || AMODE == 3) {
      const size_t row = (size_t)(row0 + R + rloc);
      if (tile < 16) return (const char*)A  + ((row * 1024 + (size_t)tile * 64) << 1) + (sw << 4);
      else           return (const char*)A2 + ((row * 1024 + (size_t)(tile - 16) * 64) << 1) + (sw << 4);
    } else if constexpr (AMODE == 1) {
      const int r = row0 + R + rloc;
      const unsigned m = (unsigned)(r & (M_DIM - 1));
      const int g = (r >> 10) * S_DIM + (int)((m * 4095u) / 1023u);
      return (const char*)A + (((size_t)g * H_DIM + (size_t)tile * 64) << 1) + (sw << 4);
    } else {
      return (const char*)Az + (((size_t)(row0 + R + rloc) * lda + (size_t)tile * 64) << 1) + (sw << 4);
    }
  };
  auto srcB = [&](int R, int tile) -> const char* {
    if constexpr (AMODE == 3) {
      const size_t row = (size_t)(col0 + R + rloc);
      if (tile < 16) return (const char*)Bw + ((row * ldb + (size_t)tile * 64) << 1) + (sw << 4);
      else           return (const char*)B2 + (((size_t)(row0 >> 12) * 1048576 +
                                                row * 1024 + (size_t)(tile - 16) * 64) << 1) + (sw << 4);
    } else {
      return (const char*)Bz + (((size_t)(col0 + R + rloc) * ldb + (size_t)tile * 64) << 1) + (sw << 4);
    }
  };
  auto SA = [&](int buf, int R, int tile) {
    async16(srcA(R, tile), (char*)&lds[buf][0][0] + (size_t)(R + w * 8) * 128);
  };
  auto SB = [&](int buf, int R, int tile) {
    async16(srcB(R, tile), (char*)&lds[buf][1][0] + (size_t)(R + w * 8) * 128);
  };

  floatx16 acc[4][2];
  {
    const floatx16 zz = {0.f,0.f,0.f,0.f,0.f,0.f,0.f,0.f,0.f,0.f,0.f,0.f,0.f,0.f,0.f,0.f};
    #pragma unroll
    for (int i = 0; i < 4; ++i)
      #pragma unroll
      for (int j = 0; j < 2; ++j)
        acc[i][j] = zz;
  }

  {
    const int t1 = (nt > 1) ? 1 : 0;
    SA(0, 0, 0);  SA(0, 64, 0); SA(0, 128, 0); SA(0, 192, 0);
    SB(0, 0, 0);  SB(0, 64, 0); SB(0, 128, 0); SB(0, 192, 0);
    SA(1, 0, t1); SA(1, 128, t1);
    SB(1, 0, t1); SB(1, 64, t1); SB(1, 128, t1); SB(1, 192, t1);
    SCHEDB();
    VMCNT(6);
    BARRIER();
  }

#define RD_A4(dst, ldsbase, Mh, kh)                                               \
  {                                                                               \
    _Pragma("unroll")                                                             \
    for (int mi = 0; mi < 4; ++mi) {                                              \
      const int fi = (Mh) * 2 + (mi >> 1);                                        \
      const int ks = (kh) * 2 + (mi & 1);                                         \
      dst[mi] = *(const short8*)((ldsbase) + aRowByte + fi * 4096 +               \
                                 ((ks * 32 + kb16) ^ aswz));                      \
    }                                                                             \
  }
#define RD_B4(dst, ldsbase, kh)                                                   \
  {                                                                               \
    _Pragma("unroll")                                                             \
    for (int ni = 0; ni < 4; ++ni) {                                              \
      const int fj = ni >> 1;                                                     \
      const int ks = (kh) * 2 + (ni & 1);                                         \
      dst[ni] = *(const short8*)((ldsbase) + bRowByte + fj * 4096 +               \
                                 ((ks * 32 + kb16) ^ aswz));                      \
    }                                                                             \
  }
#define MFMA8(Mh, av, bv)                                                         \
  {                                                                               \
    __builtin_amdgcn_s_setprio(1);                                                \
    _Pragma("unroll")                                                             \
    for (int fi_ = 0; fi_ < 2; ++fi_)                                             \
      _Pragma("unroll")                                                           \
      for (int fj_ = 0; fj_ < 2; ++fj_)                                           \
        _Pragma("unroll")                                                         \
        for (int ks_ = 0; ks_ < 2; ++ks_)                                         \
          acc[(Mh) * 2 + fi_][fj_] = __builtin_amdgcn_mfma_f32_32x32x16_bf16(     \
              av[fi_ * 2 + ks_], bv[fj_ * 2 + ks_], acc[(Mh) * 2 + fi_][fj_],     \
              0, 0, 0);                                                           \
    __builtin_amdgcn_s_setprio(0);                                                \
  }

  short8 afX[4], afY[4], bf0[4], bf1[4];

  {
    const char* L0A = (const char*)&lds[0][0][0];
    const char* L0B = (const char*)&lds[0][1][0];
    RD_A4(afX, L0A, 0, 0);
    RD_B4(bf0, L0B, 0);
  }

  for (int t = 0; t < nt; ++t) {
    const int b = t & 1;
    const char* LA  = (const char*)&lds[b][0][0];
    const char* LB  = (const char*)&lds[b][1][0];
    const char* LA1 = (const char*)&lds[b ^ 1][0][0];
    const char* LB1 = (const char*)&lds[b ^ 1][1][0];
    const int tn  = (t + 1 < nt) ? t + 1 : nt - 1;
    const int tn2 = (t + 2 < nt) ? t + 2 : nt - 1;

    RD_A4(afY, LA, 1, 0);
    SA(b ^ 1, 64, tn); SA(b ^ 1, 192, tn);
    BARRIER();
    MFMA8(0, afX, bf0);
    BARRIER();

    RD_A4(afX, LA, 0, 1);
    RD_B4(bf1, LB, 1);
    BARRIER();
    MFMA8(1, afY, bf0);
    BARRIER();

    RD_A4(afY, LA, 1, 1);
    BARRIER();
    MFMA8(0, afX, bf1);
    SCHEDB();
    VMCNT(2);
    BARRIER();

    RD_A4(afX, LA1, 0, 0);
    RD_B4(bf0, LB1, 0);
    SA(b, 0, tn2); SA(b, 128, tn2);
    SB(b, 0, tn2); SB(b, 64, tn2); SB(b, 128, tn2); SB(b, 192, tn2);
    BARRIER();
    MFMA8(1, afY, bf1);
    SCHEDB();
    VMCNT(6);
    BARRIER();
  }
#undef RD_A4
#undef RD_B4
#undef MFMA8

  SCHEDB();
  VMCNT(0);
  SCHEDB();

  OutT* Cz = C + (size_t)z * sC;
  const int rext = (l >> 5) << 2;
  #pragma unroll
  for (int fj = 0; fj < 2; ++fj) {
    const int colg = col0 + wn * 64 + fj * 32 + lc;
    float bvv = 0.f;
    if constexpr (HAS_BIAS) {
      if constexpr (EPI == 1) bvv = (colg < 1024) ? bias[colg] : bias2[colg - 1024];
      else bvv = bias[colg];
    }
    #pragma unroll
    for (int fi = 0; fi < 4; ++fi) {
      const int rbase = row0 + wm * 128 + fi * 32 + rext;
      #pragma unroll
      for (int i = 0; i < 16; ++i) {
        const float v = acc[fi][fj][i] + bvv;
        const int rr = rbase + (i & 3) + ((i >> 2) << 3);
        if constexpr (EPI == 1) {
          if (colg < 1024) ((short*)C)[(size_t)rr * 1024 + colg] = f2b(v);
          else             Cv[(size_t)rr * 1024 + (colg - 1024)] = f2b(v);
        } else {
          const size_t o = (size_t)rr * 1024 + colg;
          if constexpr (std::is_same<OutT, float>::value) Cz[o] = v;
          else Cz[o] = f2b(v);
        }
      }
    }
  }
}

// ---------------- fused row inverse-L2-norms for q (32768 rows) and k (8192 rows) ----------------
__global__ __launch_bounds__(256) void k_rownorm2(const short* __restrict__ q,
                                                  const short* __restrict__ kx,
                                                  float* __restrict__ qinv,
                                                  float* __restrict__ kinv) {
  const int w = threadIdx.x >> 6, l = threadIdx.x & 63;
  const short* x;
  float* inv;
  size_t row;
  if (blockIdx.x < 8192) { x = q;  inv = qinv; row = (size_t)blockIdx.x * 4 + w; }
  else                   { x = kx; inv = kinv; row = (size_t)(blockIdx.x - 8192) * 4 + w; }
  const short* p = x + row * 1024 + l * 16;
  short8 v0 = *(const short8*)p;
  short8 v1 = *(const short8*)(p + 8);
  float ss = 0.f;
  #pragma unroll
  for (int i = 0; i < 8; ++i) {
    const float a = b2f(v0[i]), b = b2f(v1[i]);
    ss += a * a + b * b;
  }
  #pragma unroll
  for (int o = 32; o > 0; o >>= 1) ss += __shfl_xor(ss, o, 64);
  if (l == 0) inv[row] = 1.f / fmaxf(sqrtf(ss), 1e-12f);
}

// ---------------- softmax over rows of 1024 (bf16 sb -> bf16 ab) with norm folding ----------------
__global__ __launch_bounds__(256) void k_softmax(const short* __restrict__ sbuf,
                                                 short* __restrict__ abuf,
                                                 const float* __restrict__ qinv,
                                                 const float* __restrict__ kinv) {
  const int w = threadIdx.x >> 6, l = threadIdx.x & 63;
  const size_t row = (size_t)blockIdx.x * 4 + w;
  const short* p = sbuf + row * 1024 + l * 16;
  short* po = abuf + row * 1024 + l * 16;
  const float qi = qinv[row];
  const float* kv = kinv + ((row >> 12) << 10) + l * 16;
  float ki[16];
  *(float4*)&ki[0]  = *(const float4*)(kv);
  *(float4*)&ki[4]  = *(const float4*)(kv + 4);
  *(float4*)&ki[8]  = *(const float4*)(kv + 8);
  *(float4*)&ki[12] = *(const float4*)(kv + 12);
  short8 v0 = *(const short8*)p;
  short8 v1 = *(const short8*)(p + 8);
  float f[16];
  #pragma unroll
  for (int i = 0; i < 8; ++i) {
    f[i]     = b2f(v0[i]) * qi * ki[i];
    f[8 + i] = b2f(v1[i]) * qi * ki[8 + i];
  }
  float mx = f[0];
  #pragma unroll
  for (int i = 1; i < 16; ++i) mx = fmaxf(mx, f[i]);
  #pragma unroll
  for (int o = 32; o > 0; o >>= 1) mx = fmaxf(mx, __shfl_xor(mx, o, 64));
  float s = 0.f;
  #pragma unroll
  for (int i = 0; i < 16; ++i) { f[i] = __expf(f[i] - mx); s += f[i]; }
  #pragma unroll
  for (int o = 32; o > 0; o >>= 1) s += __shfl_xor(s, o, 64);
  const float inv = 1.f / s;
  #pragma unroll
  for (int i = 0; i < 8; ++i) { v0[i] = f2b(f[i] * inv); v1[i] = f2b(f[8 + i] * inv); }
  *(short8*)po = v0;
  *(short8*)(po + 8) = v1;
}

extern "C" void kernel_launch(void* const* d_in, const int* in_sizes, int n_in,
                              void* d_out, int out_size, void* d_ws, size_t ws_size,
                              hipStream_t stream)
{
  const float* hid = (const float*)d_in[0];
  const float* Wq  = (const float*)d_in[1];
  const float* bq  = (const float*)d_in[2];
  const float* Wk  = (const float*)d_in[3];
  const float* bk  = (const float*)d_in[4];
  const float* Wv  = (const float*)d_in[5];
  const float* bv  = (const float*)d_in[6];
  const float* Wo  = (const float*)d_in[7];
  const float* bo  = (const float*)d_in[8];

  char* ws = (char*)d_ws;
  short* hb  = (short*)(ws);                          // 64 MiB  bf16 hidden
  short* qb  = (short*)(ws + (size_t)67108864);       // 64 MiB  bf16 q raw; later attn (ab)
  short* knb = (short*)(ws + (size_t)134217728);      // 16 MiB  bf16 raw keys; later vwt
  short* mvb = (short*)(ws + (size_t)150994944);      // 16 MiB  bf16 V natural [b][m][h]
  short* wqb = (short*)(ws + (size_t)167772160);      // 2 MiB
  short* wkb = (short*)(ws + (size_t)169869312);      // 2 MiB
  short* wvb = (short*)(ws + (size_t)171966464);      // 2 MiB
  short* wob = (short*)(ws + (size_t)174063616);      // 4 MiB
  short* ab  = qb;                                    // attn (bf16) over dead qb
  short* vwt = knb;                                   // VWT[b][n][m] over dead knb
  short* sb  = (short*)d_out;                         // raw scores: d_out[0,64MiB)
  float* qinv = (float*)((char*)d_out + (size_t)67108864);           // 128 KiB
  float* kinv = (float*)((char*)d_out + (size_t)67108864 + 131072);  // 32 KiB
  float* out = (float*)d_out;

  // all converts in one launch
  k_cvtall<<<4096, 256, 0, stream>>>((const float4*)hid, (const float4*)Wq,
                                     (const float4*)Wk, (const float4*)Wv, (const float4*)Wo,
                                     (short4v*)hb, (short4v*)wqb, (short4v*)wkb,
                                     (short4v*)wvb, (short4v*)wob);

  // Q projection: qb = hb @ Wq^T + bq   (32x32 variant)
  k_gemm32<0, 0, true, short><<<dim3(128, 4, 1), 512, 0, stream>>>(
      hb, nullptr, wqb, nullptr, bq, nullptr, qb, nullptr,
      1024, 1024, 1024, 0, 0, 0);
  // fused K+V projection (gathered rows): cols 0-1023 -> knb (+bk); 1024-2047 -> mvb (+bv)
  k_gemm32<1, 1, true, short><<<dim3(32, 8, 1), 512, 0, stream>>>(
      hb, nullptr, wkb, nullptr, bk, bv, knb, mvb,
      1024, 1024, 1024, 0, 0, 0);
  // fused q+k row inverse norms (read-only)
  k_rownorm2<<<10240, 256, 0, stream>>>(qb, knb, qinv, kinv);
  // scores on RAW q,k: sb[b][s][m] = q[b][s] . k[b][m]
  k_gemm32<0, 0, false, short><<<dim3(16, 4, 8), 512, 0, stream>>>(
      qb, nullptr, knb, nullptr, nullptr, nullptr, sb, nullptr,
      1024, 1024, 1024, (long)S_DIM * H_DIM, (long)M_DIM * H_DIM, (long)S_DIM * M_DIM);
  // VWT[b][n][m] = sum_h Wo[n][1024+h] * V[b][m][h]   (overwrites knb, dead after scores)
  k_gemm32<0, 0, false, short><<<dim3(4, 4, 8), 512, 0, stream>>>(
      wob + 1024, nullptr, mvb, nullptr, nullptr, nullptr, vwt, nullptr,
      1024, 2048, 1024, 0, (long)M_DIM * H_DIM, (long)M_DIM * H_DIM);
  // softmax rows with folded 1/(|q||k|) scaling: sb -> ab (over dead qb)
  k_softmax<<<8192, 256, 0, stream>>>(sb, ab, qinv, kinv);
  // output: out[r][n] = sum_k hb[r][k]*Wo[n][k] + sum_m ab[r][m]*VWT[b][n][m] + bo[n]  (16x16 variant)
  k_gemm16<3, 0, true, float><<<dim3(128, 4, 1), 512, 0, stream>>>(
      hb, ab, wob, vwt, bo, nullptr, out, nullptr,
      2048, 1024, 2048, 0, 0, 0);
}